// Round 1
// baseline (907.258 us; speedup 1.0000x reference)
//
#include <hip/hip_runtime.h>
#include <math.h>

#define BG   200
#define NPGc 512
#define EPGc 8192
#define NE   (BG*EPGc)     // 1638400
#define N0   (BG*NPGc)     // 102400
#define FINc 11
#define Hc   128
#define K1c  256
#define K2c  205
#define K3c  164
#define N1   (BG*K1c)      // 51200
#define N2   (BG*K2c)      // 41000
#define N3   (BG*K3c)      // 32800

// ---------------- CSR build (once per launch, reused by all 3 conv layers) ----
__global__ void k_deg(const int* __restrict__ dst, int* __restrict__ deg){
  int e = blockIdx.x*256 + threadIdx.x;
  if (e < NE) atomicAdd(&deg[dst[e]], 1);
}

__global__ void k_rowptr(const int* __restrict__ deg, int* __restrict__ rowptr,
                         int* __restrict__ cursor){
  __shared__ int s[NPGc];
  int g = blockIdx.x, t = threadIdx.x;
  int d = deg[g*NPGc + t];
  s[t] = d;
  __syncthreads();
  for (int o=1;o<NPGc;o<<=1){
    int v = (t>=o) ? s[t-o] : 0;
    __syncthreads();
    s[t] += v;
    __syncthreads();
  }
  int rp = g*EPGc + s[t] - d;   // exclusive scan + graph base (each graph has exactly EPGc edges)
  rowptr[g*NPGc+t] = rp;
  cursor[g*NPGc+t] = rp;
}

__global__ void k_scatter(const int* __restrict__ src, const int* __restrict__ dst,
                          int* __restrict__ cursor, int* __restrict__ csr){
  int e = blockIdx.x*256 + threadIdx.x;
  if (e < NE){
    int p = atomicAdd(&cursor[dst[e]], 1);
    csr[p] = src[e];
  }
}

// ---------------- layer 1 aggregation over raw x (FIN=11) --------------------
__global__ void k_agg1(const float* __restrict__ x, const int* __restrict__ csr,
                       const int* __restrict__ rowptr, const int* __restrict__ deg,
                       float* __restrict__ agg1){
  int gid = blockIdx.x*256 + threadIdx.x;
  int d = gid >> 4, f = gid & 15;
  if (d >= N0 || f >= FINc) return;
  int rs = rowptr[d], dg = deg[d];
  float acc = 0.f;
  for (int i=0;i<dg;i++){
    int s = csr[rs+i];
    acc += x[s*FINc + f];
  }
  agg1[d*FINc + f] = acc;
}

__global__ void k_conv1(const float* __restrict__ x, const float* __restrict__ agg1,
                        const float* __restrict__ Wrel, const float* __restrict__ Wroot,
                        const float* __restrict__ bias, float* __restrict__ h1){
  int gid = blockIdx.x*256 + threadIdx.x;
  int n = gid >> 7, j = gid & 127;
  if (n >= N0) return;
  float acc = bias[j];
  #pragma unroll
  for (int f=0; f<FINc; f++){
    acc += agg1[n*FINc+f]*Wrel[j*FINc+f] + x[n*FINc+f]*Wroot[j*FINc+f];
  }
  h1[n*Hc + j] = fmaxf(acc, 0.f);
}

// ---------------- per-node pooling score: tanh((h.pw)/||pw||) ----------------
__global__ void k_score(const float* __restrict__ h, const float* __restrict__ pw,
                        float* __restrict__ score, int M){
  int n = blockIdx.x*4 + (threadIdx.x>>6);
  int lane = threadIdx.x & 63;
  if (n >= M) return;
  float p0 = pw[lane], p1 = pw[64+lane];
  float v0 = h[n*Hc+lane], v1 = h[n*Hc+64+lane];
  float dot = v0*p0 + v1*p1;
  float nn  = p0*p0 + p1*p1;
  for (int o=32;o>0;o>>=1){ dot += __shfl_xor(dot,o); nn += __shfl_xor(nn,o); }
  if (lane==0) score[n] = tanhf(dot / sqrtf(nn));
}

// ---------------- per-graph top-k via bitonic sort (val desc, idx asc) -------
template<int N, int K, int NP2>
__global__ void k_topk(const float* __restrict__ score, int* __restrict__ newid,
                       int* __restrict__ perm){
  __shared__ float sv[NP2];
  __shared__ int   si[NP2];
  int g = blockIdx.x, t = threadIdx.x;
  sv[t] = (t < N) ? score[g*N + t] : -INFINITY;
  si[t] = t;
  __syncthreads();
  for (int k=2;k<=NP2;k<<=1){
    for (int j=k>>1;j>0;j>>=1){
      int p = t ^ j;
      if (p > t){
        float va = sv[t], vb = sv[p];
        int   ia = si[t], ib = si[p];
        bool good = (va > vb) || (va == vb && ia < ib);  // already in desc order
        bool up   = ((t & k) == 0);
        if (good != up){ sv[t]=vb; si[t]=ib; sv[p]=va; si[p]=ia; }
      }
      __syncthreads();
    }
  }
  if (t < N) newid[g*N + t] = -1;
  __syncthreads();
  if (t < K){
    int old = si[t];
    newid[g*N + old] = g*K + t;
    perm[g*K + t]    = g*N + old;
  }
}

// hp[m] = h[perm[m]] * score[perm[m]]
__global__ void k_gather(const float* __restrict__ h, const float* __restrict__ score,
                         const int* __restrict__ perm, float* __restrict__ hp, int M){
  int m = blockIdx.x*4 + (threadIdx.x>>6);
  int lane = threadIdx.x & 63;
  if (m >= M) return;
  int p = perm[m];
  float s = score[p];
  hp[m*Hc + lane]      = h[p*Hc + lane] * s;
  hp[m*Hc + 64 + lane] = h[p*Hc + 64 + lane] * s;
}

// z[g] += [max; mean] over k pooled rows
__global__ void k_readout(const float* __restrict__ hp, float* __restrict__ z, int k){
  int g = blockIdx.x, j = threadIdx.x; // 128 threads
  float mx = -INFINITY, sm = 0.f;
  const float* base = hp + (size_t)g*k*Hc + j;
  for (int r=0;r<k;r++){
    float v = base[r*Hc];
    mx = fmaxf(mx, v); sm += v;
  }
  z[g*256 + j]       += mx;
  z[g*256 + 128 + j] += sm / (float)k;
}

// ---------------- layers 2/3 aggregation: wave per ORIGINAL dst node ---------
__global__ void k_aggH(const int* __restrict__ map, const float* __restrict__ hp,
                       const int* __restrict__ csr, const int* __restrict__ rowptr,
                       const int* __restrict__ deg, float* __restrict__ agg){
  int d = blockIdx.x*4 + (threadIdx.x>>6);
  int lane = threadIdx.x & 63;
  if (d >= N0) return;
  int nd = map[d];
  if (nd < 0) return;
  int rs = rowptr[d], dg = deg[d];
  float ax = 0.f, ay = 0.f;
  for (int base=0; base<dg; base+=64){
    int e = base + lane;
    int ns = -1;
    if (e < dg){ int s = csr[rs+e]; ns = map[s]; }
    int cnt = min(64, dg-base);
    for (int jj=0;jj<cnt;jj++){
      int nsj = __shfl(ns, jj);
      if (nsj >= 0){
        float2 v = ((const float2*)(hp + (size_t)nsj*Hc))[lane];
        ax += v.x; ay += v.y;
      }
    }
  }
  ((float2*)(agg + (size_t)nd*Hc))[lane] = make_float2(ax, ay);
}

// ---------------- conv2/conv3: h = relu(agg@Wrel^T + hp@Wroot^T + b) ---------
// 64x128 tile per block (256 threads), 8x4 acc per thread; f32 VALU.
__launch_bounds__(256)
__global__ void k_convH(const float* __restrict__ agg, const float* __restrict__ hp,
                        const float* __restrict__ Wrel, const float* __restrict__ Wroot,
                        const float* __restrict__ bias, float* __restrict__ hout, int M){
  int tid = threadIdx.x;
  int n0 = blockIdx.x * 64;
  int rowg = tid >> 5, colg = tid & 31;
  float acc[8][4];
  #pragma unroll
  for (int i=0;i<8;i++)
    #pragma unroll
    for (int q=0;q<4;q++) acc[i][q]=0.f;

  #pragma unroll
  for (int part=0; part<2; part++){
    const float* A = part ? hp : agg;
    const float* W = part ? Wroot : Wrel;
    for (int kk=0; kk<Hc; kk+=4){
      float4 wB[4];
      #pragma unroll
      for (int q=0;q<4;q++)
        wB[q] = *(const float4*)&W[(colg*4+q)*Hc + kk];
      #pragma unroll
      for (int i=0;i<8;i++){
        int n = n0 + rowg*8 + i;
        if (n >= M) n = M-1;
        float4 a = *(const float4*)&A[(size_t)n*Hc + kk];
        #pragma unroll
        for (int q=0;q<4;q++)
          acc[i][q] += a.x*wB[q].x + a.y*wB[q].y + a.z*wB[q].z + a.w*wB[q].w;
      }
    }
  }
  #pragma unroll
  for (int i=0;i<8;i++){
    int n = n0 + rowg*8 + i;
    if (n < M){
      int j = colg*4;
      float4 r;
      r.x = fmaxf(acc[i][0] + bias[j+0], 0.f);
      r.y = fmaxf(acc[i][1] + bias[j+1], 0.f);
      r.z = fmaxf(acc[i][2] + bias[j+2], 0.f);
      r.w = fmaxf(acc[i][3] + bias[j+3], 0.f);
      *(float4*)&hout[(size_t)n*Hc + j] = r;
    }
  }
}

__global__ void k_compose(const int* __restrict__ map1, const int* __restrict__ newid2,
                          int* __restrict__ map2){
  int o = blockIdx.x*256 + threadIdx.x;
  if (o < N0){ int m = map1[o]; map2[o] = (m>=0) ? newid2[m] : -1; }
}

// ---------------- MLP head: 256 -> 512 -> 64 -> 1 ---------------------------
__launch_bounds__(512)
__global__ void k_mlp(const float* __restrict__ z,
                      const float* __restrict__ Wl1, const float* __restrict__ bl1,
                      const float* __restrict__ Wl2, const float* __restrict__ bl2,
                      const float* __restrict__ Wl3, const float* __restrict__ bl3,
                      float* __restrict__ out){
  __shared__ float zs[256];
  __shared__ float u1[512];
  __shared__ float u2[64];
  int g = blockIdx.x, t = threadIdx.x;
  if (t < 256) zs[t] = z[g*256 + t];
  __syncthreads();
  {
    float acc = bl1[t];
    for (int f=0; f<256; f++) acc += zs[f]*Wl1[t*256+f];
    u1[t] = fmaxf(acc, 0.f);
  }
  __syncthreads();
  if (t < 64){
    float acc = bl2[t];
    for (int f=0; f<512; f++) acc += u1[f]*Wl2[t*512+f];
    u2[t] = fmaxf(acc, 0.f);
  }
  __syncthreads();
  if (t == 0){
    float acc = bl3[0];
    for (int f=0; f<64; f++) acc += u2[f]*Wl3[f];
    out[g] = acc;
  }
}

extern "C" void kernel_launch(void* const* d_in, const int* in_sizes, int n_in,
                              void* d_out, int out_size, void* d_ws, size_t ws_size,
                              hipStream_t stream){
  const float* x     = (const float*)d_in[0];
  const int*   esrc  = (const int*)d_in[1];
  const int*   edst  = (const int*)d_in[2];
  const float* Wrel1 = (const float*)d_in[5];
  const float* Wroot1= (const float*)d_in[6];
  const float* b1    = (const float*)d_in[7];
  const float* pw1   = (const float*)d_in[8];
  const float* Wrel2 = (const float*)d_in[9];
  const float* Wroot2= (const float*)d_in[10];
  const float* b2    = (const float*)d_in[11];
  const float* pw2   = (const float*)d_in[12];
  const float* Wrel3 = (const float*)d_in[13];
  const float* Wroot3= (const float*)d_in[14];
  const float* b3    = (const float*)d_in[15];
  const float* pw3   = (const float*)d_in[16];
  const float* Wl1   = (const float*)d_in[17];
  const float* bl1   = (const float*)d_in[18];
  const float* Wl2   = (const float*)d_in[19];
  const float* bl2   = (const float*)d_in[20];
  const float* Wl3   = (const float*)d_in[21];
  const float* bl3   = (const float*)d_in[22];
  float* out = (float*)d_out;

  char* ws = (char*)d_ws;
  size_t off = 0;
  auto alloc = [&](size_t elems)->void*{
    void* p = ws + off;
    off += ((elems*4 + 255)/256)*256;
    return p;
  };
  int*   deg    = (int*)alloc(N0);
  int*   rowptr = (int*)alloc(N0);
  int*   cursor = (int*)alloc(N0);
  int*   csr    = (int*)alloc(NE);
  int*   map1   = (int*)alloc(N0);
  int*   newid2 = (int*)alloc(N1);
  int*   map2   = (int*)alloc(N0);
  int*   perm   = (int*)alloc(N1);
  float* score1 = (float*)alloc(N0);
  float* score2 = (float*)alloc(N1);
  float* score3 = (float*)alloc(N2);
  float* agg1   = (float*)alloc((size_t)N0*FINc);
  float* bigA   = (float*)alloc((size_t)N0*Hc);   // h1 -> [agg2|h2] -> [agg3|h3]
  float* hpA    = (float*)alloc((size_t)N1*Hc);   // hp1 -> hp2 -> hp3
  float* z      = (float*)alloc(BG*256);

  float* h1   = bigA;
  float* agg2 = bigA;
  float* h2   = bigA + (size_t)N1*Hc;
  float* agg3 = bigA;
  float* h3   = bigA + (size_t)N1*Hc;

  hipMemsetAsync(deg, 0, N0*sizeof(int), stream);
  hipMemsetAsync(z,   0, BG*256*sizeof(float), stream);

  // CSR build (layer-independent)
  k_deg    <<<NE/256, 256, 0, stream>>>(edst, deg);
  k_rowptr <<<BG, NPGc, 0, stream>>>(deg, rowptr, cursor);
  k_scatter<<<NE/256, 256, 0, stream>>>(esrc, edst, cursor, csr);

  // layer 1
  k_agg1  <<<N0*16/256, 256, 0, stream>>>(x, csr, rowptr, deg, agg1);
  k_conv1 <<<N0*128/256, 256, 0, stream>>>(x, agg1, Wrel1, Wroot1, b1, h1);
  k_score <<<N0/4, 256, 0, stream>>>(h1, pw1, score1, N0);
  k_topk<NPGc, K1c, 512><<<BG, 512, 0, stream>>>(score1, map1, perm);
  k_gather<<<N1/4, 256, 0, stream>>>(h1, score1, perm, hpA, N1);
  k_readout<<<BG, 128, 0, stream>>>(hpA, z, K1c);

  // layer 2
  k_aggH  <<<N0/4, 256, 0, stream>>>(map1, hpA, csr, rowptr, deg, agg2);
  k_convH <<<N1/64, 256, 0, stream>>>(agg2, hpA, Wrel2, Wroot2, b2, h2, N1);
  k_score <<<N1/4, 256, 0, stream>>>(h2, pw2, score2, N1);
  k_topk<K1c, K2c, 256><<<BG, 256, 0, stream>>>(score2, newid2, perm);
  k_compose<<<N0/256, 256, 0, stream>>>(map1, newid2, map2);
  k_gather<<<(N2+3)/4, 256, 0, stream>>>(h2, score2, perm, hpA, N2);
  k_readout<<<BG, 128, 0, stream>>>(hpA, z, K2c);

  // layer 3
  k_aggH  <<<N0/4, 256, 0, stream>>>(map2, hpA, csr, rowptr, deg, agg3);
  k_convH <<<(N2+63)/64, 256, 0, stream>>>(agg3, hpA, Wrel3, Wroot3, b3, h3, N2);
  k_score <<<(N2+3)/4, 256, 0, stream>>>(h3, pw3, score3, N2);
  k_topk<K2c, K3c, 256><<<BG, 256, 0, stream>>>(score3, newid2, perm);
  k_gather<<<(N3+3)/4, 256, 0, stream>>>(h3, score3, perm, hpA, N3);
  k_readout<<<BG, 128, 0, stream>>>(hpA, z, K3c);

  // head
  k_mlp<<<BG, 512, 0, stream>>>(z, Wl1, bl1, Wl2, bl2, Wl3, bl3, out);
}

// Round 2
// 544.969 us; speedup vs baseline: 1.6648x; 1.6648x over previous
//
#include <hip/hip_runtime.h>
#include <math.h>

#define BG   200
#define NPGc 512
#define EPGc 8192
#define NE   (BG*EPGc)     // 1638400
#define N0   (BG*NPGc)     // 102400
#define FINc 11
#define Hc   128
#define K1c  256
#define K2c  205
#define K3c  164
#define N1   (BG*K1c)      // 51200
#define N2   (BG*K2c)      // 41000
#define N3   (BG*K3c)      // 32800

// ---------------- CSR build (once per launch, reused by all 3 conv layers) ----
__global__ void k_deg(const int* __restrict__ dst, int* __restrict__ deg){
  int e = blockIdx.x*256 + threadIdx.x;
  if (e < NE) atomicAdd(&deg[dst[e]], 1);
}

__global__ void k_rowptr(const int* __restrict__ deg, int* __restrict__ rowptr,
                         int* __restrict__ cursor){
  __shared__ int s[NPGc];
  int g = blockIdx.x, t = threadIdx.x;
  int d = deg[g*NPGc + t];
  s[t] = d;
  __syncthreads();
  for (int o=1;o<NPGc;o<<=1){
    int v = (t>=o) ? s[t-o] : 0;
    __syncthreads();
    s[t] += v;
    __syncthreads();
  }
  int rp = g*EPGc + s[t] - d;
  rowptr[g*NPGc+t] = rp;
  cursor[g*NPGc+t] = rp;
}

__global__ void k_scatter(const int* __restrict__ src, const int* __restrict__ dst,
                          int* __restrict__ cursor, int* __restrict__ csr){
  int e = blockIdx.x*256 + threadIdx.x;
  if (e < NE){
    int p = atomicAdd(&cursor[dst[e]], 1);
    csr[p] = src[e];
  }
}

// ---------------- weight prep: transposes for coalesced reads ----------------
// WcatT[22][128]: f<11 -> Wrel1^T, f>=11 -> Wroot1^T
// Wl1T [256][512], Wl2T [512][64]
__global__ void k_prep(const float* __restrict__ Wrel1, const float* __restrict__ Wroot1,
                       const float* __restrict__ Wl1, const float* __restrict__ Wl2,
                       float* __restrict__ WcatT, float* __restrict__ Wl1T,
                       float* __restrict__ Wl2T){
  int idx = blockIdx.x*256 + threadIdx.x;
  if (idx < 22*128){
    int f = idx >> 7, j = idx & 127;
    WcatT[idx] = (f < 11) ? Wrel1[j*11 + f] : Wroot1[j*11 + (f-11)];
  }
  if (idx < 256*512){
    int f = idx >> 9, t = idx & 511;
    Wl1T[idx] = Wl1[t*256 + f];
  }
  if (idx < 512*64){
    int f = idx >> 6, t = idx & 63;
    Wl2T[idx] = Wl2[t*512 + f];
  }
}

// ---------------- layer 1 aggregation over raw x (FIN=11) --------------------
__global__ void k_agg1(const float* __restrict__ x, const int* __restrict__ csr,
                       const int* __restrict__ rowptr, const int* __restrict__ deg,
                       float* __restrict__ agg1){
  int gid = blockIdx.x*256 + threadIdx.x;
  int d = gid >> 4, f = gid & 15;
  if (d >= N0 || f >= FINc) return;
  int rs = rowptr[d], dg = deg[d];
  float acc = 0.f;
  for (int i=0;i<dg;i++){
    int s = csr[rs+i];
    acc += x[s*FINc + f];
  }
  agg1[d*FINc + f] = acc;
}

// conv1: thread computes node n, cols j0..j0+3. Weights via transposed WcatT.
__global__ void k_conv1(const float* __restrict__ x, const float* __restrict__ agg1,
                        const float* __restrict__ WcatT, const float* __restrict__ bias,
                        float* __restrict__ h1){
  int gid = blockIdx.x*256 + threadIdx.x;
  int n = gid >> 5, cg = gid & 31;
  if (n >= N0) return;
  int j0 = cg*4;
  float av[FINc], xv[FINc];
  #pragma unroll
  for (int f=0; f<FINc; f++){ av[f] = agg1[n*FINc+f]; xv[f] = x[n*FINc+f]; }
  float4 acc = *(const float4*)&bias[j0];
  #pragma unroll
  for (int f=0; f<FINc; f++){
    float4 wr = *(const float4*)&WcatT[f*Hc + j0];
    float4 wo = *(const float4*)&WcatT[(f+FINc)*Hc + j0];
    acc.x += av[f]*wr.x + xv[f]*wo.x;
    acc.y += av[f]*wr.y + xv[f]*wo.y;
    acc.z += av[f]*wr.z + xv[f]*wo.z;
    acc.w += av[f]*wr.w + xv[f]*wo.w;
  }
  acc.x = fmaxf(acc.x,0.f); acc.y = fmaxf(acc.y,0.f);
  acc.z = fmaxf(acc.z,0.f); acc.w = fmaxf(acc.w,0.f);
  *(float4*)&h1[(size_t)n*Hc + j0] = acc;
}

// ---------------- per-node pooling score: tanh((h.pw)/||pw||) ----------------
__global__ void k_score(const float* __restrict__ h, const float* __restrict__ pw,
                        float* __restrict__ score, int M){
  int n = blockIdx.x*4 + (threadIdx.x>>6);
  int lane = threadIdx.x & 63;
  if (n >= M) return;
  float p0 = pw[lane], p1 = pw[64+lane];
  float v0 = h[n*Hc+lane], v1 = h[n*Hc+64+lane];
  float dot = v0*p0 + v1*p1;
  float nn  = p0*p0 + p1*p1;
  for (int o=32;o>0;o>>=1){ dot += __shfl_xor(dot,o); nn += __shfl_xor(nn,o); }
  if (lane==0) score[n] = tanhf(dot / sqrtf(nn));
}

// ---------------- per-graph top-k via bitonic sort (val desc, idx asc) -------
template<int N, int K, int NP2>
__global__ void k_topk(const float* __restrict__ score, int* __restrict__ newid,
                       int* __restrict__ perm){
  __shared__ float sv[NP2];
  __shared__ int   si[NP2];
  int g = blockIdx.x, t = threadIdx.x;
  sv[t] = (t < N) ? score[g*N + t] : -INFINITY;
  si[t] = t;
  __syncthreads();
  for (int k=2;k<=NP2;k<<=1){
    for (int j=k>>1;j>0;j>>=1){
      int p = t ^ j;
      if (p > t){
        float va = sv[t], vb = sv[p];
        int   ia = si[t], ib = si[p];
        bool good = (va > vb) || (va == vb && ia < ib);
        bool up   = ((t & k) == 0);
        if (good != up){ sv[t]=vb; si[t]=ib; sv[p]=va; si[p]=ia; }
      }
      __syncthreads();
    }
  }
  if (t < N) newid[g*N + t] = -1;
  __syncthreads();
  if (t < K){
    int old = si[t];
    newid[g*N + old] = g*K + t;
    perm[g*K + t]    = g*N + old;
  }
}

// hp[m] = h[perm[m]] * score[perm[m]]
__global__ void k_gather(const float* __restrict__ h, const float* __restrict__ score,
                         const int* __restrict__ perm, float* __restrict__ hp, int M){
  int m = blockIdx.x*4 + (threadIdx.x>>6);
  int lane = threadIdx.x & 63;
  if (m >= M) return;
  int p = perm[m];
  float s = score[p];
  hp[m*Hc + lane]      = h[p*Hc + lane] * s;
  hp[m*Hc + 64 + lane] = h[p*Hc + 64 + lane] * s;
}

// z[g] += [max; mean] over k pooled rows; 512 threads = 4 row-chunks x 128 cols
__global__ void k_readout(const float* __restrict__ hp, float* __restrict__ z, int k){
  __shared__ float smx[4][Hc];
  __shared__ float ssm[4][Hc];
  int g = blockIdx.x;
  int rc = threadIdx.x >> 7, j = threadIdx.x & 127;
  float mx = -INFINITY, sm = 0.f;
  const float* base = hp + (size_t)g*k*Hc + j;
  for (int r=rc; r<k; r+=4){
    float v = base[(size_t)r*Hc];
    mx = fmaxf(mx, v); sm += v;
  }
  smx[rc][j] = mx; ssm[rc][j] = sm;
  __syncthreads();
  if (rc == 0){
    mx = fmaxf(fmaxf(smx[0][j], smx[1][j]), fmaxf(smx[2][j], smx[3][j]));
    sm = ssm[0][j] + ssm[1][j] + ssm[2][j] + ssm[3][j];
    z[g*256 + j]       += mx;
    z[g*256 + 128 + j] += sm / (float)k;
  }
}

// ---------------- layers 2/3 aggregation: wave per ORIGINAL dst node ---------
__global__ void k_aggH(const int* __restrict__ map, const float* __restrict__ hp,
                       const int* __restrict__ csr, const int* __restrict__ rowptr,
                       const int* __restrict__ deg, float* __restrict__ agg){
  int d = blockIdx.x*4 + (threadIdx.x>>6);
  int lane = threadIdx.x & 63;
  if (d >= N0) return;
  int nd = map[d];
  if (nd < 0) return;
  int rs = rowptr[d], dg = deg[d];
  float ax = 0.f, ay = 0.f;
  for (int base=0; base<dg; base+=64){
    int e = base + lane;
    int ns = -1;
    if (e < dg){ int s = csr[rs+e]; ns = map[s]; }
    int cnt = min(64, dg-base);
    for (int jj=0;jj<cnt;jj++){
      int nsj = __shfl(ns, jj);
      if (nsj >= 0){
        float2 v = ((const float2*)(hp + (size_t)nsj*Hc))[lane];
        ax += v.x; ay += v.y;
      }
    }
  }
  ((float2*)(agg + (size_t)nd*Hc))[lane] = make_float2(ax, ay);
}

// ---------------- conv2/conv3: LDS-tiled f32 GEMM ---------------------------
// C[M x 128] = relu(A0 @ W0^T + A1 @ W1^T + b), K=128 per part.
// 128x128 tile per block, BK=32, 256 threads, 8x8 acc/thread.
#define BMt 128
#define BKt 32
__launch_bounds__(256,4)
__global__ void k_convH(const float* __restrict__ A0, const float* __restrict__ A1,
                        const float* __restrict__ W0, const float* __restrict__ W1,
                        const float* __restrict__ bias, float* __restrict__ hout, int M){
  __shared__ float As[BKt][BMt];   // 16 KB
  __shared__ float Bs[BKt][Hc];    // 16 KB
  int tid = threadIdx.x;
  int m0 = blockIdx.x * BMt;
  int tm = tid >> 4, tn = tid & 15;
  float acc[8][8];
  #pragma unroll
  for (int i=0;i<8;i++)
    #pragma unroll
    for (int q=0;q<8;q++) acc[i][q] = 0.f;

  // staging: 1024 float4 per tile, 4 per thread
  int fi0 = tid*4;
  int arow = fi0 >> 3;              // same for all 4 (fi0..fi0+3 within.. fi>>3 varies)
  float4 pa[4], pb[4];

  auto load_chunk = [&](int c){
    const float* A = (c >= 4) ? A1 : A0;
    const float* W = (c >= 4) ? W1 : W0;
    int kbase = (c & 3) * BKt;
    #pragma unroll
    for (int q=0;q<4;q++){
      int fi = fi0 + q;
      int r  = fi >> 3;             // 0..127
      int k4 = (fi & 7) * 4;        // 0..28
      int gr = m0 + r; if (gr >= M) gr = M-1;
      pa[q] = *(const float4*)&A[(size_t)gr*Hc + kbase + k4];
      pb[q] = *(const float4*)&W[(size_t)r*Hc + kbase + k4];
    }
  };
  auto store_chunk = [&](){
    #pragma unroll
    for (int q=0;q<4;q++){
      int fi = fi0 + q;
      int r  = fi >> 3;
      int k4 = (fi & 7) * 4;
      As[k4+0][r] = pa[q].x; As[k4+1][r] = pa[q].y;
      As[k4+2][r] = pa[q].z; As[k4+3][r] = pa[q].w;
      Bs[k4+0][r] = pb[q].x; Bs[k4+1][r] = pb[q].y;
      Bs[k4+2][r] = pb[q].z; Bs[k4+3][r] = pb[q].w;
    }
  };

  load_chunk(0);
  for (int c=0; c<8; c++){
    __syncthreads();
    store_chunk();
    if (c < 7) load_chunk(c+1);
    __syncthreads();
    #pragma unroll 4
    for (int ks=0; ks<BKt; ks++){
      float4 a0 = *(const float4*)&As[ks][tm*8];
      float4 a1 = *(const float4*)&As[ks][tm*8+4];
      float4 b0 = *(const float4*)&Bs[ks][tn*8];
      float4 b1 = *(const float4*)&Bs[ks][tn*8+4];
      float a[8] = {a0.x,a0.y,a0.z,a0.w,a1.x,a1.y,a1.z,a1.w};
      float b[8] = {b0.x,b0.y,b0.z,b0.w,b1.x,b1.y,b1.z,b1.w};
      #pragma unroll
      for (int i=0;i<8;i++)
        #pragma unroll
        for (int q=0;q<8;q++)
          acc[i][q] = fmaf(a[i], b[q], acc[i][q]);
    }
  }

  int j0 = tn*8;
  float4 bia0 = *(const float4*)&bias[j0];
  float4 bia1 = *(const float4*)&bias[j0+4];
  #pragma unroll
  for (int i=0;i<8;i++){
    int n = m0 + tm*8 + i;
    if (n < M){
      float4 r0, r1;
      r0.x = fmaxf(acc[i][0]+bia0.x, 0.f); r0.y = fmaxf(acc[i][1]+bia0.y, 0.f);
      r0.z = fmaxf(acc[i][2]+bia0.z, 0.f); r0.w = fmaxf(acc[i][3]+bia0.w, 0.f);
      r1.x = fmaxf(acc[i][4]+bia1.x, 0.f); r1.y = fmaxf(acc[i][5]+bia1.y, 0.f);
      r1.z = fmaxf(acc[i][6]+bia1.z, 0.f); r1.w = fmaxf(acc[i][7]+bia1.w, 0.f);
      *(float4*)&hout[(size_t)n*Hc + j0]     = r0;
      *(float4*)&hout[(size_t)n*Hc + j0 + 4] = r1;
    }
  }
}

__global__ void k_compose(const int* __restrict__ map1, const int* __restrict__ newid2,
                          int* __restrict__ map2){
  int o = blockIdx.x*256 + threadIdx.x;
  if (o < N0){ int m = map1[o]; map2[o] = (m>=0) ? newid2[m] : -1; }
}

// ---------------- MLP head: 256 -> 512 -> 64 -> 1 (transposed weights) -------
__launch_bounds__(512)
__global__ void k_mlp(const float* __restrict__ z,
                      const float* __restrict__ Wl1T, const float* __restrict__ bl1,
                      const float* __restrict__ Wl2T, const float* __restrict__ bl2,
                      const float* __restrict__ Wl3, const float* __restrict__ bl3,
                      float* __restrict__ out){
  __shared__ float zs[256];
  __shared__ float u1[512];
  int g = blockIdx.x, t = threadIdx.x;
  if (t < 256) zs[t] = z[g*256 + t];
  __syncthreads();
  {
    float acc = bl1[t];
    #pragma unroll 8
    for (int f=0; f<256; f++) acc = fmaf(zs[f], Wl1T[f*512 + t], acc);
    u1[t] = fmaxf(acc, 0.f);
  }
  __syncthreads();
  if (t < 64){
    float acc = bl2[t];
    #pragma unroll 8
    for (int f=0; f<512; f++) acc = fmaf(u1[f], Wl2T[f*64 + t], acc);
    float v = fmaxf(acc, 0.f) * Wl3[t];
    for (int o=32;o>0;o>>=1) v += __shfl_xor(v, o);
    if (t == 0) out[g] = v + bl3[0];
  }
}

extern "C" void kernel_launch(void* const* d_in, const int* in_sizes, int n_in,
                              void* d_out, int out_size, void* d_ws, size_t ws_size,
                              hipStream_t stream){
  const float* x     = (const float*)d_in[0];
  const int*   esrc  = (const int*)d_in[1];
  const int*   edst  = (const int*)d_in[2];
  const float* Wrel1 = (const float*)d_in[5];
  const float* Wroot1= (const float*)d_in[6];
  const float* b1    = (const float*)d_in[7];
  const float* pw1   = (const float*)d_in[8];
  const float* Wrel2 = (const float*)d_in[9];
  const float* Wroot2= (const float*)d_in[10];
  const float* b2    = (const float*)d_in[11];
  const float* pw2   = (const float*)d_in[12];
  const float* Wrel3 = (const float*)d_in[13];
  const float* Wroot3= (const float*)d_in[14];
  const float* b3    = (const float*)d_in[15];
  const float* pw3   = (const float*)d_in[16];
  const float* Wl1   = (const float*)d_in[17];
  const float* bl1   = (const float*)d_in[18];
  const float* Wl2   = (const float*)d_in[19];
  const float* bl2   = (const float*)d_in[20];
  const float* Wl3   = (const float*)d_in[21];
  const float* bl3   = (const float*)d_in[22];
  float* out = (float*)d_out;

  char* ws = (char*)d_ws;
  size_t off = 0;
  auto alloc = [&](size_t elems)->void*{
    void* p = ws + off;
    off += ((elems*4 + 255)/256)*256;
    return p;
  };
  int*   deg    = (int*)alloc(N0);
  int*   rowptr = (int*)alloc(N0);
  int*   cursor = (int*)alloc(N0);
  int*   csr    = (int*)alloc(NE);
  int*   map1   = (int*)alloc(N0);
  int*   newid2 = (int*)alloc(N1);
  int*   map2   = (int*)alloc(N0);
  int*   perm   = (int*)alloc(N1);
  float* score1 = (float*)alloc(N0);
  float* score2 = (float*)alloc(N1);
  float* score3 = (float*)alloc(N2);
  float* agg1   = (float*)alloc((size_t)N0*FINc);
  float* WcatT  = (float*)alloc(22*Hc);
  float* Wl1T   = (float*)alloc(256*512);
  float* Wl2T   = (float*)alloc(512*64);
  float* bigA   = (float*)alloc((size_t)N0*Hc);   // h1 -> [agg2|h2] -> [agg3|h3]
  float* hpA    = (float*)alloc((size_t)N1*Hc);   // hp1 -> hp2 -> hp3
  float* z      = (float*)alloc(BG*256);

  float* h1   = bigA;
  float* agg2 = bigA;
  float* h2   = bigA + (size_t)N1*Hc;
  float* agg3 = bigA;
  float* h3   = bigA + (size_t)N1*Hc;

  hipMemsetAsync(deg, 0, N0*sizeof(int), stream);
  hipMemsetAsync(z,   0, BG*256*sizeof(float), stream);

  // CSR build + weight prep
  k_deg    <<<NE/256, 256, 0, stream>>>(edst, deg);
  k_rowptr <<<BG, NPGc, 0, stream>>>(deg, rowptr, cursor);
  k_scatter<<<NE/256, 256, 0, stream>>>(esrc, edst, cursor, csr);
  k_prep   <<<512, 256, 0, stream>>>(Wrel1, Wroot1, Wl1, Wl2, WcatT, Wl1T, Wl2T);

  // layer 1
  k_agg1  <<<N0*16/256, 256, 0, stream>>>(x, csr, rowptr, deg, agg1);
  k_conv1 <<<N0*32/256, 256, 0, stream>>>(x, agg1, WcatT, b1, h1);
  k_score <<<N0/4, 256, 0, stream>>>(h1, pw1, score1, N0);
  k_topk<NPGc, K1c, 512><<<BG, 512, 0, stream>>>(score1, map1, perm);
  k_gather<<<N1/4, 256, 0, stream>>>(h1, score1, perm, hpA, N1);
  k_readout<<<BG, 512, 0, stream>>>(hpA, z, K1c);

  // layer 2
  k_aggH  <<<N0/4, 256, 0, stream>>>(map1, hpA, csr, rowptr, deg, agg2);
  k_convH <<<N1/BMt, 256, 0, stream>>>(agg2, hpA, Wrel2, Wroot2, b2, h2, N1);
  k_score <<<N1/4, 256, 0, stream>>>(h2, pw2, score2, N1);
  k_topk<K1c, K2c, 256><<<BG, 256, 0, stream>>>(score2, newid2, perm);
  k_compose<<<N0/256, 256, 0, stream>>>(map1, newid2, map2);
  k_gather<<<(N2+3)/4, 256, 0, stream>>>(h2, score2, perm, hpA, N2);
  k_readout<<<BG, 512, 0, stream>>>(hpA, z, K2c);

  // layer 3
  k_aggH  <<<N0/4, 256, 0, stream>>>(map2, hpA, csr, rowptr, deg, agg3);
  k_convH <<<(N2+BMt-1)/BMt, 256, 0, stream>>>(agg3, hpA, Wrel3, Wroot3, b3, h3, N2);
  k_score <<<(N2+3)/4, 256, 0, stream>>>(h3, pw3, score3, N2);
  k_topk<K2c, K3c, 256><<<BG, 256, 0, stream>>>(score3, newid2, perm);
  k_gather<<<(N3+3)/4, 256, 0, stream>>>(h3, score3, perm, hpA, N3);
  k_readout<<<BG, 512, 0, stream>>>(hpA, z, K3c);

  // head
  k_mlp<<<BG, 512, 0, stream>>>(z, Wl1T, bl1, Wl2T, bl2, Wl3, bl3, out);
}

// Round 4
// 531.694 us; speedup vs baseline: 1.7064x; 1.0250x over previous
//
#include <hip/hip_runtime.h>
#include <math.h>

#define BG   200
#define NPGc 512
#define EPGc 8192
#define NE   (BG*EPGc)     // 1638400
#define N0   (BG*NPGc)     // 102400
#define FINc 11
#define Hc   128
#define K1c  256
#define K2c  205
#define K3c  164
#define N1   (BG*K1c)      // 51200
#define N2   (BG*K2c)      // 41000
#define N3   (BG*K3c)      // 32800

typedef float f32x4 __attribute__((ext_vector_type(4)));
typedef short s16x8 __attribute__((ext_vector_type(8)));

#define PLSTR ((size_t)N1*Hc)   // bf16 split-plane stride (elements)

// ---- 3-way RNE bf16 split: v = p0 + p1 + p2 + O(2^-24 |v|) -----------------
__device__ inline unsigned short bf16_rne(float v){
  unsigned u = __float_as_uint(v);
  unsigned r = u + 0x7FFFu + ((u >> 16) & 1u);
  return (unsigned short)(r >> 16);
}
__device__ inline float bf16_f32(unsigned short h){
  return __uint_as_float(((unsigned)h) << 16);
}
__device__ inline void split3(float v, unsigned short& r0, unsigned short& r1,
                              unsigned short& r2){
  r0 = bf16_rne(v); float v1 = v - bf16_f32(r0);
  r1 = bf16_rne(v1); float v2 = v1 - bf16_f32(r1);
  r2 = bf16_rne(v2);
}

// ---------------- CSR build (once per launch, reused by all 3 conv layers) ----
__global__ void k_deg(const int* __restrict__ dst, int* __restrict__ deg){
  int e = blockIdx.x*256 + threadIdx.x;
  if (e < NE) atomicAdd(&deg[dst[e]], 1);
}

__global__ void k_rowptr(const int* __restrict__ deg, int* __restrict__ rowptr,
                         int* __restrict__ cursor){
  __shared__ int s[NPGc];
  int g = blockIdx.x, t = threadIdx.x;
  int d = deg[g*NPGc + t];
  s[t] = d;
  __syncthreads();
  for (int o=1;o<NPGc;o<<=1){
    int v = (t>=o) ? s[t-o] : 0;
    __syncthreads();
    s[t] += v;
    __syncthreads();
  }
  int rp = g*EPGc + s[t] - d;
  rowptr[g*NPGc+t] = rp;
  cursor[g*NPGc+t] = rp;
}

__global__ void k_scatter(const int* __restrict__ src, const int* __restrict__ dst,
                          int* __restrict__ cursor, int* __restrict__ csr){
  int e = blockIdx.x*256 + threadIdx.x;
  if (e < NE){
    int p = atomicAdd(&cursor[dst[e]], 1);
    csr[p] = src[e];
  }
}

// ---------------- weight prep ------------------------------------------------
__global__ void k_prep(const float* __restrict__ Wrel1, const float* __restrict__ Wroot1,
                       const float* __restrict__ Wl1, const float* __restrict__ Wl2,
                       float* __restrict__ WcatT, float* __restrict__ Wl1T,
                       float* __restrict__ Wl2T){
  int idx = blockIdx.x*256 + threadIdx.x;
  if (idx < 22*128){
    int f = idx >> 7, j = idx & 127;
    WcatT[idx] = (f < 11) ? Wrel1[j*11 + f] : Wroot1[j*11 + (f-11)];
  }
  if (idx < 256*512){
    int f = idx >> 9, t = idx & 511;
    Wl1T[idx] = Wl1[t*256 + f];
  }
  if (idx < 512*64){
    int f = idx >> 6, t = idx & 63;
    Wl2T[idx] = Wl2[t*512 + f];
  }
}

// split W2/W3 into 3 RNE bf16 planes: Wsp[((L*2+p)*3+s)*16384 + c*128 + k]
__global__ void k_prepw(const float* __restrict__ Wrel2, const float* __restrict__ Wroot2,
                        const float* __restrict__ Wrel3, const float* __restrict__ Wroot3,
                        unsigned short* __restrict__ Wsp){
  int t = blockIdx.x*256 + threadIdx.x;   // 0..65535
  if (t >= 65536) return;
  int L = t >> 15, rem = t & 32767;
  int p = rem >> 14; int ck = rem & 16383;
  const float* W = L ? (p ? Wroot3 : Wrel3) : (p ? Wroot2 : Wrel2);
  unsigned short r0, r1, r2;
  split3(W[ck], r0, r1, r2);
  unsigned short* base = Wsp + (size_t)((L*2+p)*3)*16384;
  base[ck]           = r0;
  base[16384  + ck]  = r1;
  base[32768  + ck]  = r2;
}

// ---------------- layer 1 aggregation over raw x (FIN=11) --------------------
__global__ void k_agg1(const float* __restrict__ x, const int* __restrict__ csr,
                       const int* __restrict__ rowptr, const int* __restrict__ deg,
                       float* __restrict__ agg1){
  int bid = (int)((blockIdx.x & 7)*800 + (blockIdx.x >> 3));  // XCD-contiguous
  int gid = bid*256 + threadIdx.x;
  int d = gid >> 4, f = gid & 15;
  if (d >= N0 || f >= FINc) return;
  int rs = rowptr[d], dg = deg[d];
  float acc = 0.f;
  for (int i=0;i<dg;i++){
    int s = csr[rs+i];
    acc += x[s*FINc + f];
  }
  agg1[d*FINc + f] = acc;
}

__global__ void k_conv1(const float* __restrict__ x, const float* __restrict__ agg1,
                        const float* __restrict__ WcatT, const float* __restrict__ bias,
                        float* __restrict__ h1){
  int gid = blockIdx.x*256 + threadIdx.x;
  int n = gid >> 5, cg = gid & 31;
  if (n >= N0) return;
  int j0 = cg*4;
  float av[FINc], xv[FINc];
  #pragma unroll
  for (int f=0; f<FINc; f++){ av[f] = agg1[n*FINc+f]; xv[f] = x[n*FINc+f]; }
  float4 acc = *(const float4*)&bias[j0];
  #pragma unroll
  for (int f=0; f<FINc; f++){
    float4 wr = *(const float4*)&WcatT[f*Hc + j0];
    float4 wo = *(const float4*)&WcatT[(f+FINc)*Hc + j0];
    acc.x += av[f]*wr.x + xv[f]*wo.x;
    acc.y += av[f]*wr.y + xv[f]*wo.y;
    acc.z += av[f]*wr.z + xv[f]*wo.z;
    acc.w += av[f]*wr.w + xv[f]*wo.w;
  }
  acc.x = fmaxf(acc.x,0.f); acc.y = fmaxf(acc.y,0.f);
  acc.z = fmaxf(acc.z,0.f); acc.w = fmaxf(acc.w,0.f);
  *(float4*)&h1[(size_t)n*Hc + j0] = acc;
}

// ---------------- per-node pooling score -------------------------------------
__global__ void k_score(const float* __restrict__ h, const float* __restrict__ pw,
                        float* __restrict__ score, int M){
  int n = blockIdx.x*4 + (threadIdx.x>>6);
  int lane = threadIdx.x & 63;
  if (n >= M) return;
  float p0 = pw[lane], p1 = pw[64+lane];
  float v0 = h[n*Hc+lane], v1 = h[n*Hc+64+lane];
  float dot = v0*p0 + v1*p1;
  float nn  = p0*p0 + p1*p1;
  for (int o=32;o>0;o>>=1){ dot += __shfl_xor(dot,o); nn += __shfl_xor(nn,o); }
  if (lane==0) score[n] = tanhf(dot / sqrtf(nn));
}

// ---------------- per-graph top-k via bitonic sort (val desc, idx asc) -------
template<int N, int K, int NP2>
__global__ void k_topk(const float* __restrict__ score, int* __restrict__ newid,
                       int* __restrict__ perm){
  __shared__ float sv[NP2];
  __shared__ int   si[NP2];
  int g = blockIdx.x, t = threadIdx.x;
  sv[t] = (t < N) ? score[g*N + t] : -INFINITY;
  si[t] = t;
  __syncthreads();
  for (int k=2;k<=NP2;k<<=1){
    for (int j=k>>1;j>0;j>>=1){
      int p = t ^ j;
      if (p > t){
        float va = sv[t], vb = sv[p];
        int   ia = si[t], ib = si[p];
        bool good = (va > vb) || (va == vb && ia < ib);
        bool up   = ((t & k) == 0);
        if (good != up){ sv[t]=vb; si[t]=ib; sv[p]=va; si[p]=ia; }
      }
      __syncthreads();
    }
  }
  if (t < N) newid[g*N + t] = -1;
  __syncthreads();
  if (t < K){
    int old = si[t];
    newid[g*N + old] = g*K + t;
    perm[g*K + t]    = g*N + old;
  }
}

__global__ void k_gather(const float* __restrict__ h, const float* __restrict__ score,
                         const int* __restrict__ perm, float* __restrict__ hp, int M){
  int m = blockIdx.x*4 + (threadIdx.x>>6);
  int lane = threadIdx.x & 63;
  if (m >= M) return;
  int p = perm[m];
  float s = score[p];
  hp[m*Hc + lane]      = h[p*Hc + lane] * s;
  hp[m*Hc + 64 + lane] = h[p*Hc + 64 + lane] * s;
}

__global__ void k_readout(const float* __restrict__ hp, float* __restrict__ z, int k){
  __shared__ float smx[4][Hc];
  __shared__ float ssm[4][Hc];
  int g = blockIdx.x;
  int rc = threadIdx.x >> 7, j = threadIdx.x & 127;
  float mx = -INFINITY, sm = 0.f;
  const float* base = hp + (size_t)g*k*Hc + j;
  for (int r=rc; r<k; r+=4){
    float v = base[(size_t)r*Hc];
    mx = fmaxf(mx, v); sm += v;
  }
  smx[rc][j] = mx; ssm[rc][j] = sm;
  __syncthreads();
  if (rc == 0){
    mx = fmaxf(fmaxf(smx[0][j], smx[1][j]), fmaxf(smx[2][j], smx[3][j]));
    sm = ssm[0][j] + ssm[1][j] + ssm[2][j] + ssm[3][j];
    z[g*256 + j]       += mx;
    z[g*256 + 128 + j] += sm / (float)k;
  }
}

// ---------------- layers 2/3 aggregation, fused 3-plane bf16 split output ----
__global__ void k_aggHs(const int* __restrict__ map, const float* __restrict__ hp,
                        const int* __restrict__ csr, const int* __restrict__ rowptr,
                        const int* __restrict__ deg, unsigned short* __restrict__ aggS){
  int bid = (int)((blockIdx.x & 7)*3200 + (blockIdx.x >> 3));
  int d = bid*4 + (threadIdx.x>>6);
  int lane = threadIdx.x & 63;
  if (d >= N0) return;
  int nd = map[d];
  if (nd < 0) return;
  int rs = rowptr[d], dg = deg[d];
  float ax = 0.f, ay = 0.f;
  for (int base=0; base<dg; base+=64){
    int e = base + lane;
    int ns = -1;
    if (e < dg){ int s = csr[rs+e]; ns = map[s]; }
    int cnt = min(64, dg-base);
    for (int jj=0;jj<cnt;jj++){
      int nsj = __shfl(ns, jj);
      if (nsj >= 0){
        float2 v = ((const float2*)(hp + (size_t)nsj*Hc))[lane];
        ax += v.x; ay += v.y;
      }
    }
  }
  unsigned short x0,x1,x2,y0,y1,y2;
  split3(ax, x0, x1, x2);
  split3(ay, y0, y1, y2);
  unsigned* p0 = (unsigned*)(aggS             + (size_t)nd*Hc);
  unsigned* p1 = (unsigned*)(aggS + PLSTR     + (size_t)nd*Hc);
  unsigned* p2 = (unsigned*)(aggS + 2*PLSTR   + (size_t)nd*Hc);
  p0[lane] = (unsigned)x0 | ((unsigned)y0 << 16);
  p1[lane] = (unsigned)x1 | ((unsigned)y1 << 16);
  p2[lane] = (unsigned)x2 | ((unsigned)y2 << 16);
}

// ---------------- conv2/conv3: 6-term split-bf16 MFMA GEMM -------------------
// C = relu(agg @ Wrel^T + hp @ Wroot^T + b), f32-equivalent precision.
// agg pre-split (3 planes), hp split inline, W pre-split (3 planes).
// Block: 64 rows x 128 cols, 4 waves (2x2 of 32x64). No LDS.
__launch_bounds__(256)
__global__ void k_convH(const unsigned short* __restrict__ A0s, const float* __restrict__ A1,
                        const unsigned short* __restrict__ Wsp,  // [p][3s][128c][128k]
                        const float* __restrict__ bias, float* __restrict__ hout, int M){
  int tid = threadIdx.x;
  int w = tid >> 6, l = tid & 63;
  int wm = w >> 1, wn = w & 1;
  int lr = l & 15, lk = l >> 4;
  int m0 = blockIdx.x * 64;

  f32x4 acc[2][4];
  #pragma unroll
  for (int mi=0;mi<2;mi++)
    #pragma unroll
    for (int ni=0;ni<4;ni++) acc[mi][ni] = (f32x4){0.f,0.f,0.f,0.f};

  #pragma unroll
  for (int kc=0; kc<4; kc++){
    int kb = kc*32 + lk*8;
    s16x8 a0[2], a1[2], a2[2];

    // ---- part 0: agg (pre-split planes) ----
    #pragma unroll
    for (int mi=0; mi<2; mi++){
      int row = m0 + wm*32 + mi*16 + lr; if (row >= M) row = M-1;
      const unsigned short* ap = A0s + (size_t)row*Hc + kb;
      a0[mi] = *(const s16x8*)(ap);
      a1[mi] = *(const s16x8*)(ap + PLSTR);
      a2[mi] = *(const s16x8*)(ap + 2*PLSTR);
    }
    #pragma unroll
    for (int ni=0; ni<4; ni++){
      int col = wn*64 + ni*16 + lr;
      const unsigned short* bp = Wsp + col*Hc + kb;
      s16x8 b0 = *(const s16x8*)bp;
      s16x8 b1 = *(const s16x8*)(bp + 16384);
      s16x8 b2 = *(const s16x8*)(bp + 32768);
      #pragma unroll
      for (int mi=0; mi<2; mi++){
        acc[mi][ni] = __builtin_amdgcn_mfma_f32_16x16x32_bf16(a0[mi], b0, acc[mi][ni], 0,0,0);
        acc[mi][ni] = __builtin_amdgcn_mfma_f32_16x16x32_bf16(a0[mi], b1, acc[mi][ni], 0,0,0);
        acc[mi][ni] = __builtin_amdgcn_mfma_f32_16x16x32_bf16(a1[mi], b0, acc[mi][ni], 0,0,0);
        acc[mi][ni] = __builtin_amdgcn_mfma_f32_16x16x32_bf16(a1[mi], b1, acc[mi][ni], 0,0,0);
        acc[mi][ni] = __builtin_amdgcn_mfma_f32_16x16x32_bf16(a0[mi], b2, acc[mi][ni], 0,0,0);
        acc[mi][ni] = __builtin_amdgcn_mfma_f32_16x16x32_bf16(a2[mi], b0, acc[mi][ni], 0,0,0);
      }
    }

    // ---- part 1: hp (f32, inline RNE 3-split) ----
    #pragma unroll
    for (int mi=0; mi<2; mi++){
      int row = m0 + wm*32 + mi*16 + lr; if (row >= M) row = M-1;
      const float* ap = A1 + (size_t)row*Hc + kb;
      float av[8];
      *(float4*)&av[0] = *(const float4*)ap;
      *(float4*)&av[4] = *(const float4*)(ap+4);
      #pragma unroll
      for (int j=0;j<8;j++){
        unsigned short r0,r1,r2;
        split3(av[j], r0, r1, r2);
        a0[mi][j] = (short)r0; a1[mi][j] = (short)r1; a2[mi][j] = (short)r2;
      }
    }
    #pragma unroll
    for (int ni=0; ni<4; ni++){
      int col = wn*64 + ni*16 + lr;
      const unsigned short* bp = Wsp + 3*16384 + col*Hc + kb;
      s16x8 b0 = *(const s16x8*)bp;
      s16x8 b1 = *(const s16x8*)(bp + 16384);
      s16x8 b2 = *(const s16x8*)(bp + 32768);
      #pragma unroll
      for (int mi=0; mi<2; mi++){
        acc[mi][ni] = __builtin_amdgcn_mfma_f32_16x16x32_bf16(a0[mi], b0, acc[mi][ni], 0,0,0);
        acc[mi][ni] = __builtin_amdgcn_mfma_f32_16x16x32_bf16(a0[mi], b1, acc[mi][ni], 0,0,0);
        acc[mi][ni] = __builtin_amdgcn_mfma_f32_16x16x32_bf16(a1[mi], b0, acc[mi][ni], 0,0,0);
        acc[mi][ni] = __builtin_amdgcn_mfma_f32_16x16x32_bf16(a1[mi], b1, acc[mi][ni], 0,0,0);
        acc[mi][ni] = __builtin_amdgcn_mfma_f32_16x16x32_bf16(a0[mi], b2, acc[mi][ni], 0,0,0);
        acc[mi][ni] = __builtin_amdgcn_mfma_f32_16x16x32_bf16(a2[mi], b0, acc[mi][ni], 0,0,0);
      }
    }
  }

  // epilogue: D reg -> row=(l>>4)*4+reg, col=l&15 within 16x16 tile
  #pragma unroll
  for (int mi=0; mi<2; mi++){
    #pragma unroll
    for (int reg=0; reg<4; reg++){
      int row = m0 + wm*32 + mi*16 + lk*4 + reg;
      if (row < M){
        #pragma unroll
        for (int ni=0; ni<4; ni++){
          int col = wn*64 + ni*16 + lr;
          hout[(size_t)row*Hc + col] = fmaxf(acc[mi][ni][reg] + bias[col], 0.f);
        }
      }
    }
  }
}

__global__ void k_compose(const int* __restrict__ map1, const int* __restrict__ newid2,
                          int* __restrict__ map2){
  int o = blockIdx.x*256 + threadIdx.x;
  if (o < N0){ int m = map1[o]; map2[o] = (m>=0) ? newid2[m] : -1; }
}

// ---------------- MLP head ---------------------------------------------------
__launch_bounds__(512)
__global__ void k_mlp(const float* __restrict__ z,
                      const float* __restrict__ Wl1T, const float* __restrict__ bl1,
                      const float* __restrict__ Wl2T, const float* __restrict__ bl2,
                      const float* __restrict__ Wl3, const float* __restrict__ bl3,
                      float* __restrict__ out){
  __shared__ float zs[256];
  __shared__ float u1[512];
  int g = blockIdx.x, t = threadIdx.x;
  if (t < 256) zs[t] = z[g*256 + t];
  __syncthreads();
  {
    float acc = bl1[t];
    #pragma unroll 8
    for (int f=0; f<256; f++) acc = fmaf(zs[f], Wl1T[f*512 + t], acc);
    u1[t] = fmaxf(acc, 0.f);
  }
  __syncthreads();
  if (t < 64){
    float acc = bl2[t];
    #pragma unroll 8
    for (int f=0; f<512; f++) acc = fmaf(u1[f], Wl2T[f*64 + t], acc);
    float v = fmaxf(acc, 0.f) * Wl3[t];
    for (int o=32;o>0;o>>=1) v += __shfl_xor(v, o);
    if (t == 0) out[g] = v + bl3[0];
  }
}

extern "C" void kernel_launch(void* const* d_in, const int* in_sizes, int n_in,
                              void* d_out, int out_size, void* d_ws, size_t ws_size,
                              hipStream_t stream){
  const float* x     = (const float*)d_in[0];
  const int*   esrc  = (const int*)d_in[1];
  const int*   edst  = (const int*)d_in[2];
  const float* Wrel1 = (const float*)d_in[5];
  const float* Wroot1= (const float*)d_in[6];
  const float* b1    = (const float*)d_in[7];
  const float* pw1   = (const float*)d_in[8];
  const float* Wrel2 = (const float*)d_in[9];
  const float* Wroot2= (const float*)d_in[10];
  const float* b2    = (const float*)d_in[11];
  const float* pw2   = (const float*)d_in[12];
  const float* Wrel3 = (const float*)d_in[13];
  const float* Wroot3= (const float*)d_in[14];
  const float* b3    = (const float*)d_in[15];
  const float* pw3   = (const float*)d_in[16];
  const float* Wl1   = (const float*)d_in[17];
  const float* bl1   = (const float*)d_in[18];
  const float* Wl2   = (const float*)d_in[19];
  const float* bl2   = (const float*)d_in[20];
  const float* Wl3   = (const float*)d_in[21];
  const float* bl3   = (const float*)d_in[22];
  float* out = (float*)d_out;

  char* ws = (char*)d_ws;
  size_t off = 0;
  auto alloc = [&](size_t elems)->void*{
    void* p = ws + off;
    off += ((elems*4 + 255)/256)*256;
    return p;
  };
  int*   deg    = (int*)alloc(N0);
  int*   rowptr = (int*)alloc(N0);
  int*   cursor = (int*)alloc(N0);
  int*   csr    = (int*)alloc(NE);
  int*   map1   = (int*)alloc(N0);
  int*   newid2 = (int*)alloc(N1);
  int*   map2   = (int*)alloc(N0);
  int*   perm   = (int*)alloc(N1);
  float* score1 = (float*)alloc(N0);
  float* score2 = (float*)alloc(N1);
  float* score3 = (float*)alloc(N2);
  float* agg1   = (float*)alloc((size_t)N0*FINc);
  float* WcatT  = (float*)alloc(22*Hc);
  float* Wl1T   = (float*)alloc(256*512);
  float* Wl2T   = (float*)alloc(512*64);
  unsigned short* Wsp = (unsigned short*)alloc(98304);  // 2L x 2p x 3s x 16384 bf16
  float* bigA   = (float*)alloc((size_t)N0*Hc);   // h1, then aggS (3 bf16 planes)
  float* hB     = (float*)alloc((size_t)N1*Hc);   // h2 -> h3
  float* hpA    = (float*)alloc((size_t)N1*Hc);   // hp1 -> hp2 -> hp3
  float* z      = (float*)alloc(BG*256);

  float* h1   = bigA;
  unsigned short* aggS = (unsigned short*)bigA;   // 39.3 MB <= 52.4 MB, h1 dead by then
  float* h2   = hB;
  float* h3   = hB;

  hipMemsetAsync(deg, 0, N0*sizeof(int), stream);
  hipMemsetAsync(z,   0, BG*256*sizeof(float), stream);

  // CSR build + weight prep
  k_deg    <<<NE/256, 256, 0, stream>>>(edst, deg);
  k_rowptr <<<BG, NPGc, 0, stream>>>(deg, rowptr, cursor);
  k_scatter<<<NE/256, 256, 0, stream>>>(esrc, edst, cursor, csr);
  k_prep   <<<512, 256, 0, stream>>>(Wrel1, Wroot1, Wl1, Wl2, WcatT, Wl1T, Wl2T);
  k_prepw  <<<256, 256, 0, stream>>>(Wrel2, Wroot2, Wrel3, Wroot3, Wsp);

  // layer 1
  k_agg1  <<<N0*16/256, 256, 0, stream>>>(x, csr, rowptr, deg, agg1);
  k_conv1 <<<N0*32/256, 256, 0, stream>>>(x, agg1, WcatT, b1, h1);
  k_score <<<N0/4, 256, 0, stream>>>(h1, pw1, score1, N0);
  k_topk<NPGc, K1c, 512><<<BG, 512, 0, stream>>>(score1, map1, perm);
  k_gather<<<N1/4, 256, 0, stream>>>(h1, score1, perm, hpA, N1);
  k_readout<<<BG, 512, 0, stream>>>(hpA, z, K1c);

  // layer 2
  k_aggHs <<<N0/4, 256, 0, stream>>>(map1, hpA, csr, rowptr, deg, aggS);
  k_convH <<<N1/64, 256, 0, stream>>>(aggS, hpA, Wsp, b2, h2, N1);
  k_score <<<N1/4, 256, 0, stream>>>(h2, pw2, score2, N1);
  k_topk<K1c, K2c, 256><<<BG, 256, 0, stream>>>(score2, newid2, perm);
  k_compose<<<N0/256, 256, 0, stream>>>(map1, newid2, map2);
  k_gather<<<(N2+3)/4, 256, 0, stream>>>(h2, score2, perm, hpA, N2);
  k_readout<<<BG, 512, 0, stream>>>(hpA, z, K2c);

  // layer 3
  k_aggHs <<<N0/4, 256, 0, stream>>>(map2, hpA, csr, rowptr, deg, aggS);
  k_convH <<<(N2+63)/64, 256, 0, stream>>>(aggS, hpA, Wsp + 98304, b3, h3, N2);
  k_score <<<(N2+3)/4, 256, 0, stream>>>(h3, pw3, score3, N2);
  k_topk<K2c, K3c, 256><<<BG, 256, 0, stream>>>(score3, newid2, perm);
  k_gather<<<(N3+3)/4, 256, 0, stream>>>(h3, score3, perm, hpA, N3);
  k_readout<<<BG, 512, 0, stream>>>(hpA, z, K3c);

  // head
  k_mlp<<<BG, 512, 0, stream>>>(z, Wl1T, bl1, Wl2T, bl2, Wl3, bl3, out);
}

// Round 5
// 481.508 us; speedup vs baseline: 1.8842x; 1.1042x over previous
//
#include <hip/hip_runtime.h>
#include <math.h>

#define BG   200
#define NPGc 512
#define EPGc 8192
#define NE   (BG*EPGc)     // 1638400
#define N0   (BG*NPGc)     // 102400
#define FINc 11
#define Hc   128
#define K1c  256
#define K2c  205
#define K3c  164
#define N1   (BG*K1c)      // 51200
#define N2   (BG*K2c)      // 41000
#define N3   (BG*K3c)      // 32800

typedef float f32x4 __attribute__((ext_vector_type(4)));
typedef short s16x8 __attribute__((ext_vector_type(8)));

#define PL ((size_t)N1*Hc)   // bf16 split-plane stride (elements)

// ---- 3-way RNE bf16 split: v = p0 + p1 + p2 + O(2^-24 |v|) -----------------
__device__ inline unsigned short bf16_rne(float v){
  unsigned u = __float_as_uint(v);
  unsigned r = u + 0x7FFFu + ((u >> 16) & 1u);
  return (unsigned short)(r >> 16);
}
__device__ inline float bf16_f32(unsigned short h){
  return __uint_as_float(((unsigned)h) << 16);
}
__device__ inline void split3(float v, unsigned short& r0, unsigned short& r1,
                              unsigned short& r2){
  r0 = bf16_rne(v); float v1 = v - bf16_f32(r0);
  r1 = bf16_rne(v1); float v2 = v1 - bf16_f32(r1);
  r2 = bf16_rne(v2);
}

// MFMA-fragment-native tile layout: elem (row,k) -> [row>>4][k>>3][row&15][k&7]
// A wave's A/B fragment load (16 rows x 8 k) is one contiguous 1KB read.
__device__ inline size_t flIdx(int row, int k){
  return ((size_t)(row >> 4))*2048 + (size_t)(k >> 3)*128
       + (size_t)(row & 15)*8 + (size_t)(k & 7);
}

// ---------------- CSR build (once per launch, reused by all 3 conv layers) ----
__global__ void k_deg(const int* __restrict__ dst, int* __restrict__ deg){
  int e = blockIdx.x*256 + threadIdx.x;
  if (e < NE) atomicAdd(&deg[dst[e]], 1);
}

__global__ void k_rowptr(const int* __restrict__ deg, int* __restrict__ rowptr,
                         int* __restrict__ cursor){
  __shared__ int s[NPGc];
  int g = blockIdx.x, t = threadIdx.x;
  int d = deg[g*NPGc + t];
  s[t] = d;
  __syncthreads();
  for (int o=1;o<NPGc;o<<=1){
    int v = (t>=o) ? s[t-o] : 0;
    __syncthreads();
    s[t] += v;
    __syncthreads();
  }
  int rp = g*EPGc + s[t] - d;
  rowptr[g*NPGc+t] = rp;
  cursor[g*NPGc+t] = rp;
}

__global__ void k_scatter(const int* __restrict__ src, const int* __restrict__ dst,
                          int* __restrict__ cursor, int* __restrict__ csr){
  int e = blockIdx.x*256 + threadIdx.x;
  if (e < NE){
    int p = atomicAdd(&cursor[dst[e]], 1);
    csr[p] = src[e];
  }
}

// ---------------- weight prep ------------------------------------------------
__global__ void k_prep(const float* __restrict__ Wrel1, const float* __restrict__ Wroot1,
                       const float* __restrict__ Wl1, const float* __restrict__ Wl2,
                       float* __restrict__ WcatT, float* __restrict__ Wl1T,
                       float* __restrict__ Wl2T){
  int idx = blockIdx.x*256 + threadIdx.x;
  if (idx < 22*128){
    int f = idx >> 7, j = idx & 127;
    WcatT[idx] = (f < 11) ? Wrel1[j*11 + f] : Wroot1[j*11 + (f-11)];
  }
  if (idx < 256*512){
    int f = idx >> 9, t = idx & 511;
    Wl1T[idx] = Wl1[t*256 + f];
  }
  if (idx < 512*64){
    int f = idx >> 6, t = idx & 63;
    Wl2T[idx] = Wl2[t*512 + f];
  }
}

// split W2/W3 into 3 RNE bf16 planes, fragment-native layout.
// Wsp[((L*2+p)*3+s)*16384 + flIdx(col,k)]
__global__ void k_prepw(const float* __restrict__ Wrel2, const float* __restrict__ Wroot2,
                        const float* __restrict__ Wrel3, const float* __restrict__ Wroot3,
                        unsigned short* __restrict__ Wsp){
  int t = blockIdx.x*256 + threadIdx.x;   // 0..65535
  if (t >= 65536) return;
  int L = t >> 15, p = (t >> 14) & 1, ck = t & 16383;
  int c = ck >> 7, k = ck & 127;
  const float* W = L ? (p ? Wroot3 : Wrel3) : (p ? Wroot2 : Wrel2);
  unsigned short r0, r1, r2;
  split3(W[c*128 + k], r0, r1, r2);
  unsigned short* base = Wsp + (size_t)((L*2+p)*3)*16384;
  size_t fl = flIdx(c, k);
  base[fl]          = r0;
  base[16384 + fl]  = r1;
  base[32768 + fl]  = r2;
}

// ---------------- layer 1 aggregation over raw x (FIN=11) --------------------
__global__ void k_agg1(const float* __restrict__ x, const int* __restrict__ csr,
                       const int* __restrict__ rowptr, const int* __restrict__ deg,
                       float* __restrict__ agg1){
  int bid = (int)((blockIdx.x & 7)*800 + (blockIdx.x >> 3));  // XCD-contiguous
  int gid = bid*256 + threadIdx.x;
  int d = gid >> 4, f = gid & 15;
  if (d >= N0 || f >= FINc) return;
  int rs = rowptr[d], dg = deg[d];
  float acc = 0.f;
  for (int i=0;i<dg;i++){
    int s = csr[rs+i];
    acc += x[s*FINc + f];
  }
  agg1[d*FINc + f] = acc;
}

__global__ void k_conv1(const float* __restrict__ x, const float* __restrict__ agg1,
                        const float* __restrict__ WcatT, const float* __restrict__ bias,
                        float* __restrict__ h1){
  int gid = blockIdx.x*256 + threadIdx.x;
  int n = gid >> 5, cg = gid & 31;
  if (n >= N0) return;
  int j0 = cg*4;
  float av[FINc], xv[FINc];
  #pragma unroll
  for (int f=0; f<FINc; f++){ av[f] = agg1[n*FINc+f]; xv[f] = x[n*FINc+f]; }
  float4 acc = *(const float4*)&bias[j0];
  #pragma unroll
  for (int f=0; f<FINc; f++){
    float4 wr = *(const float4*)&WcatT[f*Hc + j0];
    float4 wo = *(const float4*)&WcatT[(f+FINc)*Hc + j0];
    acc.x += av[f]*wr.x + xv[f]*wo.x;
    acc.y += av[f]*wr.y + xv[f]*wo.y;
    acc.z += av[f]*wr.z + xv[f]*wo.z;
    acc.w += av[f]*wr.w + xv[f]*wo.w;
  }
  acc.x = fmaxf(acc.x,0.f); acc.y = fmaxf(acc.y,0.f);
  acc.z = fmaxf(acc.z,0.f); acc.w = fmaxf(acc.w,0.f);
  *(float4*)&h1[(size_t)n*Hc + j0] = acc;
}

// ---------------- per-node pooling score -------------------------------------
__global__ void k_score(const float* __restrict__ h, const float* __restrict__ pw,
                        float* __restrict__ score, int M){
  int n = blockIdx.x*4 + (threadIdx.x>>6);
  int lane = threadIdx.x & 63;
  if (n >= M) return;
  float p0 = pw[lane], p1 = pw[64+lane];
  float v0 = h[n*Hc+lane], v1 = h[n*Hc+64+lane];
  float dot = v0*p0 + v1*p1;
  float nn  = p0*p0 + p1*p1;
  for (int o=32;o>0;o>>=1){ dot += __shfl_xor(dot,o); nn += __shfl_xor(nn,o); }
  if (lane==0) score[n] = tanhf(dot / sqrtf(nn));
}

// ---------------- per-graph top-k via bitonic sort (val desc, idx asc) -------
template<int N, int K, int NP2>
__global__ void k_topk(const float* __restrict__ score, int* __restrict__ newid,
                       int* __restrict__ perm){
  __shared__ float sv[NP2];
  __shared__ int   si[NP2];
  int g = blockIdx.x, t = threadIdx.x;
  sv[t] = (t < N) ? score[g*N + t] : -INFINITY;
  si[t] = t;
  __syncthreads();
  for (int k=2;k<=NP2;k<<=1){
    for (int j=k>>1;j>0;j>>=1){
      int p = t ^ j;
      if (p > t){
        float va = sv[t], vb = sv[p];
        int   ia = si[t], ib = si[p];
        bool good = (va > vb) || (va == vb && ia < ib);
        bool up   = ((t & k) == 0);
        if (good != up){ sv[t]=vb; si[t]=ib; sv[p]=va; si[p]=ia; }
      }
      __syncthreads();
    }
  }
  if (t < N) newid[g*N + t] = -1;
  __syncthreads();
  if (t < K){
    int old = si[t];
    newid[g*N + old] = g*K + t;
    perm[g*K + t]    = g*N + old;
  }
}

// hp[m] = h[perm[m]]*score[perm[m]]; also emit pre-split fragment planes hpS
__global__ void k_gather(const float* __restrict__ h, const float* __restrict__ score,
                         const int* __restrict__ perm, float* __restrict__ hp,
                         unsigned short* __restrict__ hpS, int M, int doSplit){
  int m = blockIdx.x*4 + (threadIdx.x>>6);
  int l = threadIdx.x & 63;
  if (m >= M) return;
  int p = perm[m];
  float s = score[p];
  float2 v = ((const float2*)(h + (size_t)p*Hc))[l];
  v.x *= s; v.y *= s;
  ((float2*)(hp + (size_t)m*Hc))[l] = v;
  if (doSplit){
    unsigned short x0,x1,x2,y0,y1,y2;
    split3(v.x, x0, x1, x2);
    split3(v.y, y0, y1, y2);
    size_t fl = flIdx(m, 2*l);      // even -> u32-aligned
    *(unsigned*)&hpS[fl]        = (unsigned)x0 | ((unsigned)y0 << 16);
    *(unsigned*)&hpS[PL + fl]   = (unsigned)x1 | ((unsigned)y1 << 16);
    *(unsigned*)&hpS[2*PL + fl] = (unsigned)x2 | ((unsigned)y2 << 16);
  }
}

__global__ void k_readout(const float* __restrict__ hp, float* __restrict__ z, int k){
  __shared__ float smx[4][Hc];
  __shared__ float ssm[4][Hc];
  int g = blockIdx.x;
  int rc = threadIdx.x >> 7, j = threadIdx.x & 127;
  float mx = -INFINITY, sm = 0.f;
  const float* base = hp + (size_t)g*k*Hc + j;
  for (int r=rc; r<k; r+=4){
    float v = base[(size_t)r*Hc];
    mx = fmaxf(mx, v); sm += v;
  }
  smx[rc][j] = mx; ssm[rc][j] = sm;
  __syncthreads();
  if (rc == 0){
    mx = fmaxf(fmaxf(smx[0][j], smx[1][j]), fmaxf(smx[2][j], smx[3][j]));
    sm = ssm[0][j] + ssm[1][j] + ssm[2][j] + ssm[3][j];
    z[g*256 + j]       += mx;
    z[g*256 + 128 + j] += sm / (float)k;
  }
}

// ---------------- layers 2/3 aggregation, fragment-native split output -------
__global__ void k_aggHs(const int* __restrict__ map, const float* __restrict__ hp,
                        const int* __restrict__ csr, const int* __restrict__ rowptr,
                        const int* __restrict__ deg, unsigned short* __restrict__ aggS){
  int bid = (int)((blockIdx.x & 7)*3200 + (blockIdx.x >> 3));
  int d = bid*4 + (threadIdx.x>>6);
  int lane = threadIdx.x & 63;
  if (d >= N0) return;
  int nd = map[d];
  if (nd < 0) return;
  int rs = rowptr[d], dg = deg[d];
  float ax = 0.f, ay = 0.f;
  for (int base=0; base<dg; base+=64){
    int e = base + lane;
    int ns = -1;
    if (e < dg){ int s = csr[rs+e]; ns = map[s]; }
    int cnt = min(64, dg-base);
    for (int jj=0;jj<cnt;jj++){
      int nsj = __shfl(ns, jj);
      if (nsj >= 0){
        float2 v = ((const float2*)(hp + (size_t)nsj*Hc))[lane];
        ax += v.x; ay += v.y;
      }
    }
  }
  unsigned short x0,x1,x2,y0,y1,y2;
  split3(ax, x0, x1, x2);
  split3(ay, y0, y1, y2);
  size_t fl = flIdx(nd, 2*lane);
  *(unsigned*)&aggS[fl]        = (unsigned)x0 | ((unsigned)y0 << 16);
  *(unsigned*)&aggS[PL + fl]   = (unsigned)x1 | ((unsigned)y1 << 16);
  *(unsigned*)&aggS[2*PL + fl] = (unsigned)x2 | ((unsigned)y2 << 16);
}

// ---------------- conv2/conv3: 6-term split-bf16 MFMA GEMM -------------------
// All operands pre-split + fragment-native: every load is coalesced s16x8.
// Block: 64 rows x 128 cols, 4 waves (2x2 of 32x64). Term-major MFMA order
// gives 8 independent accumulators between dependent MFMAs.
__launch_bounds__(256)
__global__ void k_convH(const unsigned short* __restrict__ A0s,
                        const unsigned short* __restrict__ A1s,
                        const unsigned short* __restrict__ Wsp,  // [p][3s][fl 16384]
                        const float* __restrict__ bias, float* __restrict__ hout, int M){
  int tid = threadIdx.x;
  int w = tid >> 6, l = tid & 63;
  int wm = w >> 1, wn = w & 1;
  int lr = l & 15, lk = l >> 4;
  int m0 = blockIdx.x * 64;

  f32x4 acc[2][4];
  #pragma unroll
  for (int mi=0;mi<2;mi++)
    #pragma unroll
    for (int ni=0;ni<4;ni++) acc[mi][ni] = (f32x4){0.f,0.f,0.f,0.f};

  #pragma unroll
  for (int kc=0; kc<4; kc++){
    #pragma unroll
    for (int p=0; p<2; p++){
      const unsigned short* As = p ? A1s : A0s;
      const unsigned short* Wp = Wsp + (size_t)p*3*16384;
      s16x8 af[3][2], bf[3][4];
      #pragma unroll
      for (int mi=0; mi<2; mi++){
        int tile = (m0 + wm*32 + mi*16) >> 4;
        size_t idx = (size_t)tile*2048 + (size_t)(kc*4+lk)*128 + (size_t)lr*8;
        af[0][mi] = *(const s16x8*)&As[idx];
        af[1][mi] = *(const s16x8*)&As[PL + idx];
        af[2][mi] = *(const s16x8*)&As[2*PL + idx];
      }
      #pragma unroll
      for (int ni=0; ni<4; ni++){
        int ct = wn*4 + ni;
        size_t idx = (size_t)ct*2048 + (size_t)(kc*4+lk)*128 + (size_t)lr*8;
        bf[0][ni] = *(const s16x8*)&Wp[idx];
        bf[1][ni] = *(const s16x8*)&Wp[16384 + idx];
        bf[2][ni] = *(const s16x8*)&Wp[32768 + idx];
      }
      #define TRM(sa,sb) \
        _Pragma("unroll") \
        for (int ni=0; ni<4; ni++){ \
          _Pragma("unroll") \
          for (int mi=0; mi<2; mi++){ \
            acc[mi][ni] = __builtin_amdgcn_mfma_f32_16x16x32_bf16(af[sa][mi], bf[sb][ni], acc[mi][ni], 0,0,0); \
          } \
        }
      TRM(0,0) TRM(0,1) TRM(1,0) TRM(1,1) TRM(0,2) TRM(2,0)
      #undef TRM
    }
  }

  // epilogue: D reg -> row=(l>>4)*4+reg, col=l&15 within 16x16 tile
  #pragma unroll
  for (int mi=0; mi<2; mi++){
    #pragma unroll
    for (int reg=0; reg<4; reg++){
      int row = m0 + wm*32 + mi*16 + lk*4 + reg;
      if (row < M){
        #pragma unroll
        for (int ni=0; ni<4; ni++){
          int col = wn*64 + ni*16 + lr;
          hout[(size_t)row*Hc + col] = fmaxf(acc[mi][ni][reg] + bias[col], 0.f);
        }
      }
    }
  }
}

__global__ void k_compose(const int* __restrict__ map1, const int* __restrict__ newid2,
                          int* __restrict__ map2){
  int o = blockIdx.x*256 + threadIdx.x;
  if (o < N0){ int m = map1[o]; map2[o] = (m>=0) ? newid2[m] : -1; }
}

// ---------------- MLP head ---------------------------------------------------
__launch_bounds__(512)
__global__ void k_mlp(const float* __restrict__ z,
                      const float* __restrict__ Wl1T, const float* __restrict__ bl1,
                      const float* __restrict__ Wl2T, const float* __restrict__ bl2,
                      const float* __restrict__ Wl3, const float* __restrict__ bl3,
                      float* __restrict__ out){
  __shared__ float zs[256];
  __shared__ float u1[512];
  int g = blockIdx.x, t = threadIdx.x;
  if (t < 256) zs[t] = z[g*256 + t];
  __syncthreads();
  {
    float acc = bl1[t];
    #pragma unroll 8
    for (int f=0; f<256; f++) acc = fmaf(zs[f], Wl1T[f*512 + t], acc);
    u1[t] = fmaxf(acc, 0.f);
  }
  __syncthreads();
  if (t < 64){
    float acc = bl2[t];
    #pragma unroll 8
    for (int f=0; f<512; f++) acc = fmaf(u1[f], Wl2T[f*64 + t], acc);
    float v = fmaxf(acc, 0.f) * Wl3[t];
    for (int o=32;o>0;o>>=1) v += __shfl_xor(v, o);
    if (t == 0) out[g] = v + bl3[0];
  }
}

extern "C" void kernel_launch(void* const* d_in, const int* in_sizes, int n_in,
                              void* d_out, int out_size, void* d_ws, size_t ws_size,
                              hipStream_t stream){
  const float* x     = (const float*)d_in[0];
  const int*   esrc  = (const int*)d_in[1];
  const int*   edst  = (const int*)d_in[2];
  const float* Wrel1 = (const float*)d_in[5];
  const float* Wroot1= (const float*)d_in[6];
  const float* b1    = (const float*)d_in[7];
  const float* pw1   = (const float*)d_in[8];
  const float* Wrel2 = (const float*)d_in[9];
  const float* Wroot2= (const float*)d_in[10];
  const float* b2    = (const float*)d_in[11];
  const float* pw2   = (const float*)d_in[12];
  const float* Wrel3 = (const float*)d_in[13];
  const float* Wroot3= (const float*)d_in[14];
  const float* b3    = (const float*)d_in[15];
  const float* pw3   = (const float*)d_in[16];
  const float* Wl1   = (const float*)d_in[17];
  const float* bl1   = (const float*)d_in[18];
  const float* Wl2   = (const float*)d_in[19];
  const float* bl2   = (const float*)d_in[20];
  const float* Wl3   = (const float*)d_in[21];
  const float* bl3   = (const float*)d_in[22];
  float* out = (float*)d_out;

  char* ws = (char*)d_ws;
  size_t off = 0;
  auto alloc = [&](size_t elems)->void*{
    void* p = ws + off;
    off += ((elems*4 + 255)/256)*256;
    return p;
  };
  int*   deg    = (int*)alloc(N0);
  int*   rowptr = (int*)alloc(N0);
  int*   cursor = (int*)alloc(N0);
  int*   csr    = (int*)alloc(NE);
  int*   map1   = (int*)alloc(N0);
  int*   newid2 = (int*)alloc(N1);
  int*   map2   = (int*)alloc(N0);
  int*   perm   = (int*)alloc(N1);
  float* score1 = (float*)alloc(N0);
  float* score2 = (float*)alloc(N1);
  float* score3 = (float*)alloc(N2);
  float* agg1   = (float*)alloc((size_t)N0*FINc);
  float* WcatT  = (float*)alloc(22*Hc);
  float* Wl1T   = (float*)alloc(256*512);
  float* Wl2T   = (float*)alloc(512*64);
  unsigned short* Wsp = (unsigned short*)alloc(98304/2*4/4*2);  // 2L x 2p x 3s x 16384 bf16 = 393KB? (elems*4B alloc: pass bf16elems/2)
  // NOTE: alloc() sizes in 4B units; Wsp needs 196608 bf16 elems = 98304 u32
  float* bigA   = (float*)alloc((size_t)N0*Hc);      // h1, then aggS (3 bf16 planes)
  float* hB     = (float*)alloc((size_t)N1*Hc);      // h2 -> h3
  float* hpA    = (float*)alloc((size_t)N1*Hc);      // hp1 -> hp2 -> hp3 (f32 row-major)
  unsigned short* hpS = (unsigned short*)alloc((size_t)3*N1*Hc/2);  // 3 bf16 planes, fragment layout
  float* z      = (float*)alloc(BG*256);

  float* h1   = bigA;
  unsigned short* aggS = (unsigned short*)bigA;   // 39.3 MB <= 52.4 MB, h1 dead by then
  float* h2   = hB;
  float* h3   = hB;

  hipMemsetAsync(deg, 0, N0*sizeof(int), stream);
  hipMemsetAsync(z,   0, BG*256*sizeof(float), stream);

  // CSR build + weight prep
  k_deg    <<<NE/256, 256, 0, stream>>>(edst, deg);
  k_rowptr <<<BG, NPGc, 0, stream>>>(deg, rowptr, cursor);
  k_scatter<<<NE/256, 256, 0, stream>>>(esrc, edst, cursor, csr);
  k_prep   <<<512, 256, 0, stream>>>(Wrel1, Wroot1, Wl1, Wl2, WcatT, Wl1T, Wl2T);
  k_prepw  <<<256, 256, 0, stream>>>(Wrel2, Wroot2, Wrel3, Wroot3, Wsp);

  // layer 1
  k_agg1  <<<N0*16/256, 256, 0, stream>>>(x, csr, rowptr, deg, agg1);
  k_conv1 <<<N0*32/256, 256, 0, stream>>>(x, agg1, WcatT, b1, h1);
  k_score <<<N0/4, 256, 0, stream>>>(h1, pw1, score1, N0);
  k_topk<NPGc, K1c, 512><<<BG, 512, 0, stream>>>(score1, map1, perm);
  k_gather<<<N1/4, 256, 0, stream>>>(h1, score1, perm, hpA, hpS, N1, 1);
  k_readout<<<BG, 512, 0, stream>>>(hpA, z, K1c);

  // layer 2
  k_aggHs <<<N0/4, 256, 0, stream>>>(map1, hpA, csr, rowptr, deg, aggS);
  k_convH <<<N1/64, 256, 0, stream>>>(aggS, hpS, Wsp, b2, h2, N1);
  k_score <<<N1/4, 256, 0, stream>>>(h2, pw2, score2, N1);
  k_topk<K1c, K2c, 256><<<BG, 256, 0, stream>>>(score2, newid2, perm);
  k_compose<<<N0/256, 256, 0, stream>>>(map1, newid2, map2);
  k_gather<<<(N2+3)/4, 256, 0, stream>>>(h2, score2, perm, hpA, hpS, N2, 1);
  k_readout<<<BG, 512, 0, stream>>>(hpA, z, K2c);

  // layer 3
  k_aggHs <<<N0/4, 256, 0, stream>>>(map2, hpA, csr, rowptr, deg, aggS);
  k_convH <<<(N2+63)/64, 256, 0, stream>>>(aggS, hpS, Wsp + 98304, b3, h3, N2);
  k_score <<<(N2+3)/4, 256, 0, stream>>>(h3, pw3, score3, N2);
  k_topk<K2c, K3c, 256><<<BG, 256, 0, stream>>>(score3, newid2, perm);
  k_gather<<<(N3+3)/4, 256, 0, stream>>>(h3, score3, perm, hpA, hpS, N3, 0);
  k_readout<<<BG, 512, 0, stream>>>(hpA, z, K3c);

  // head
  k_mlp<<<BG, 512, 0, stream>>>(z, Wl1T, bl1, Wl2T, bl2, Wl3, bl3, out);
}

// Round 6
// 458.558 us; speedup vs baseline: 1.9785x; 1.0500x over previous
//
#include <hip/hip_runtime.h>
#include <math.h>

#define BG   200
#define NPGc 512
#define EPGc 8192
#define NE   (BG*EPGc)     // 1638400
#define N0   (BG*NPGc)     // 102400
#define FINc 11
#define Hc   128
#define K1c  256
#define K2c  205
#define K3c  164
#define N1   (BG*K1c)      // 51200
#define N2   (BG*K2c)      // 41000
#define N3   (BG*K3c)      // 32800

typedef float f32x4 __attribute__((ext_vector_type(4)));
typedef short s16x8 __attribute__((ext_vector_type(8)));

#define PL ((size_t)N1*Hc)   // bf16 split-plane stride (elements)

// ---- 3-way RNE bf16 split: v = p0 + p1 + p2 + O(2^-24 |v|) -----------------
__device__ inline unsigned short bf16_rne(float v){
  unsigned u = __float_as_uint(v);
  unsigned r = u + 0x7FFFu + ((u >> 16) & 1u);
  return (unsigned short)(r >> 16);
}
__device__ inline float bf16_f32(unsigned short h){
  return __uint_as_float(((unsigned)h) << 16);
}
__device__ inline void split3(float v, unsigned short& r0, unsigned short& r1,
                              unsigned short& r2){
  r0 = bf16_rne(v); float v1 = v - bf16_f32(r0);
  r1 = bf16_rne(v1); float v2 = v1 - bf16_f32(r1);
  r2 = bf16_rne(v2);
}

// MFMA-fragment-native tile layout: elem (row,k) -> [row>>4][k>>3][row&15][k&7]
__device__ inline size_t flIdx(int row, int k){
  return ((size_t)(row >> 4))*2048 + (size_t)(k >> 3)*128
       + (size_t)(row & 15)*8 + (size_t)(k & 7);
}

// ---------------- CSR build (once per launch, reused by all 3 conv layers) ----
__global__ void k_deg(const int* __restrict__ dst, int* __restrict__ deg){
  int e = blockIdx.x*256 + threadIdx.x;
  if (e < NE) atomicAdd(&deg[dst[e]], 1);
}

__global__ void k_rowptr(const int* __restrict__ deg, int* __restrict__ rowptr,
                         int* __restrict__ cursor){
  __shared__ int s[NPGc];
  int g = blockIdx.x, t = threadIdx.x;
  int d = deg[g*NPGc + t];
  s[t] = d;
  __syncthreads();
  for (int o=1;o<NPGc;o<<=1){
    int v = (t>=o) ? s[t-o] : 0;
    __syncthreads();
    s[t] += v;
    __syncthreads();
  }
  int rp = g*EPGc + s[t] - d;
  rowptr[g*NPGc+t] = rp;
  cursor[g*NPGc+t] = rp;
}

__global__ void k_scatter(const int* __restrict__ src, const int* __restrict__ dst,
                          int* __restrict__ cursor, int* __restrict__ csr){
  int e = blockIdx.x*256 + threadIdx.x;
  if (e < NE){
    int p = atomicAdd(&cursor[dst[e]], 1);
    csr[p] = src[e];
  }
}

// ---------------- weight prep ------------------------------------------------
__global__ void k_prep(const float* __restrict__ Wrel1, const float* __restrict__ Wroot1,
                       const float* __restrict__ Wl1, const float* __restrict__ Wl2,
                       float* __restrict__ WcatT, float* __restrict__ Wl1T,
                       float* __restrict__ Wl2T){
  int idx = blockIdx.x*256 + threadIdx.x;
  if (idx < 22*128){
    int f = idx >> 7, j = idx & 127;
    WcatT[idx] = (f < 11) ? Wrel1[j*11 + f] : Wroot1[j*11 + (f-11)];
  }
  if (idx < 256*512){
    int f = idx >> 9, t = idx & 511;
    Wl1T[idx] = Wl1[t*256 + f];
  }
  if (idx < 512*64){
    int f = idx >> 6, t = idx & 63;
    Wl2T[idx] = Wl2[t*512 + f];
  }
}

// split W2/W3 into 3 RNE bf16 planes, fragment-native layout.
__global__ void k_prepw(const float* __restrict__ Wrel2, const float* __restrict__ Wroot2,
                        const float* __restrict__ Wrel3, const float* __restrict__ Wroot3,
                        unsigned short* __restrict__ Wsp){
  int t = blockIdx.x*256 + threadIdx.x;   // 0..65535
  if (t >= 65536) return;
  int L = t >> 15, p = (t >> 14) & 1, ck = t & 16383;
  int c = ck >> 7, k = ck & 127;
  const float* W = L ? (p ? Wroot3 : Wrel3) : (p ? Wroot2 : Wrel2);
  unsigned short r0, r1, r2;
  split3(W[c*128 + k], r0, r1, r2);
  unsigned short* base = Wsp + (size_t)((L*2+p)*3)*16384;
  size_t fl = flIdx(c, k);
  base[fl]          = r0;
  base[16384 + fl]  = r1;
  base[32768 + fl]  = r2;
}

// ---------------- layer 1 aggregation: wave per dst, 4 edge-slots x 16 cols --
__global__ void k_agg1(const float* __restrict__ x, const int* __restrict__ csr,
                       const int* __restrict__ rowptr, const int* __restrict__ deg,
                       float* __restrict__ agg1){
  int bid = (int)((blockIdx.x & 7)*3200 + (blockIdx.x >> 3));  // XCD-contiguous
  int d = bid*4 + (threadIdx.x >> 6);
  if (d >= N0) return;
  int lane = threadIdx.x & 63;
  int slot = lane >> 4, f = lane & 15;
  int rs = rowptr[d], dg = deg[d];
  float a0 = 0.f, a1 = 0.f;
  for (int base=0; base<dg; base+=64){
    int e = base + lane;
    int s = 0;
    if (e < dg) s = csr[rs+e];
    int cnt = min(64, dg-base);
    for (int jj=0; jj<cnt; jj+=8){
      int s0 = __shfl(s, (jj + slot) & 63);
      int s1 = __shfl(s, (jj + 4 + slot) & 63);
      if (jj + slot < cnt && f < FINc)     a0 += x[s0*FINc + f];
      if (jj + 4 + slot < cnt && f < FINc) a1 += x[s1*FINc + f];
    }
  }
  a0 += a1;
  a0 += __shfl_xor(a0, 16);
  a0 += __shfl_xor(a0, 32);
  if (slot == 0 && f < FINc) agg1[d*FINc + f] = a0;
}

__global__ void k_conv1(const float* __restrict__ x, const float* __restrict__ agg1,
                        const float* __restrict__ WcatT, const float* __restrict__ bias,
                        float* __restrict__ h1){
  int gid = blockIdx.x*256 + threadIdx.x;
  int n = gid >> 5, cg = gid & 31;
  if (n >= N0) return;
  int j0 = cg*4;
  float av[FINc], xv[FINc];
  #pragma unroll
  for (int f=0; f<FINc; f++){ av[f] = agg1[n*FINc+f]; xv[f] = x[n*FINc+f]; }
  float4 acc = *(const float4*)&bias[j0];
  #pragma unroll
  for (int f=0; f<FINc; f++){
    float4 wr = *(const float4*)&WcatT[f*Hc + j0];
    float4 wo = *(const float4*)&WcatT[(f+FINc)*Hc + j0];
    acc.x += av[f]*wr.x + xv[f]*wo.x;
    acc.y += av[f]*wr.y + xv[f]*wo.y;
    acc.z += av[f]*wr.z + xv[f]*wo.z;
    acc.w += av[f]*wr.w + xv[f]*wo.w;
  }
  acc.x = fmaxf(acc.x,0.f); acc.y = fmaxf(acc.y,0.f);
  acc.z = fmaxf(acc.z,0.f); acc.w = fmaxf(acc.w,0.f);
  *(float4*)&h1[(size_t)n*Hc + j0] = acc;
}

// ---------------- per-node pooling score -------------------------------------
__global__ void k_score(const float* __restrict__ h, const float* __restrict__ pw,
                        float* __restrict__ score, int M){
  int n = blockIdx.x*4 + (threadIdx.x>>6);
  int lane = threadIdx.x & 63;
  if (n >= M) return;
  float p0 = pw[lane], p1 = pw[64+lane];
  float v0 = h[n*Hc+lane], v1 = h[n*Hc+64+lane];
  float dot = v0*p0 + v1*p1;
  float nn  = p0*p0 + p1*p1;
  for (int o=32;o>0;o>>=1){ dot += __shfl_xor(dot,o); nn += __shfl_xor(nn,o); }
  if (lane==0) score[n] = tanhf(dot / sqrtf(nn));
}

// ---------------- per-graph top-k via bitonic sort (val desc, idx asc) -------
template<int N, int K, int NP2>
__global__ void k_topk(const float* __restrict__ score, int* __restrict__ newid,
                       int* __restrict__ perm){
  __shared__ float sv[NP2];
  __shared__ int   si[NP2];
  int g = blockIdx.x, t = threadIdx.x;
  sv[t] = (t < N) ? score[g*N + t] : -INFINITY;
  si[t] = t;
  __syncthreads();
  for (int k=2;k<=NP2;k<<=1){
    for (int j=k>>1;j>0;j>>=1){
      int p = t ^ j;
      if (p > t){
        float va = sv[t], vb = sv[p];
        int   ia = si[t], ib = si[p];
        bool good = (va > vb) || (va == vb && ia < ib);
        bool up   = ((t & k) == 0);
        if (good != up){ sv[t]=vb; si[t]=ib; sv[p]=va; si[p]=ia; }
      }
      __syncthreads();
    }
  }
  if (t < N) newid[g*N + t] = -1;
  __syncthreads();
  if (t < K){
    int old = si[t];
    newid[g*N + old] = g*K + t;
    perm[g*K + t]    = g*N + old;
  }
}

// hp[m] = h[perm[m]]*score[perm[m]]; also emit pre-split fragment planes hpS
__global__ void k_gather(const float* __restrict__ h, const float* __restrict__ score,
                         const int* __restrict__ perm, float* __restrict__ hp,
                         unsigned short* __restrict__ hpS, int M, int doSplit){
  int m = blockIdx.x*4 + (threadIdx.x>>6);
  int l = threadIdx.x & 63;
  if (m >= M) return;
  int p = perm[m];
  float s = score[p];
  float2 v = ((const float2*)(h + (size_t)p*Hc))[l];
  v.x *= s; v.y *= s;
  ((float2*)(hp + (size_t)m*Hc))[l] = v;
  if (doSplit){
    unsigned short x0,x1,x2,y0,y1,y2;
    split3(v.x, x0, x1, x2);
    split3(v.y, y0, y1, y2);
    size_t fl = flIdx(m, 2*l);
    *(unsigned*)&hpS[fl]        = (unsigned)x0 | ((unsigned)y0 << 16);
    *(unsigned*)&hpS[PL + fl]   = (unsigned)x1 | ((unsigned)y1 << 16);
    *(unsigned*)&hpS[2*PL + fl] = (unsigned)x2 | ((unsigned)y2 << 16);
  }
}

__global__ void k_readout(const float* __restrict__ hp, float* __restrict__ z, int k){
  __shared__ float smx[4][Hc];
  __shared__ float ssm[4][Hc];
  int g = blockIdx.x;
  int rc = threadIdx.x >> 7, j = threadIdx.x & 127;
  float mx = -INFINITY, sm = 0.f;
  const float* base = hp + (size_t)g*k*Hc + j;
  for (int r=rc; r<k; r+=4){
    float v = base[(size_t)r*Hc];
    mx = fmaxf(mx, v); sm += v;
  }
  smx[rc][j] = mx; ssm[rc][j] = sm;
  __syncthreads();
  if (rc == 0){
    mx = fmaxf(fmaxf(smx[0][j], smx[1][j]), fmaxf(smx[2][j], smx[3][j]));
    sm = ssm[0][j] + ssm[1][j] + ssm[2][j] + ssm[3][j];
    z[g*256 + j]       += mx;
    z[g*256 + 128 + j] += sm / (float)k;
  }
}

// orig3[m] = perm1[perm2[m]]
__global__ void k_origmap(const int* __restrict__ perm1, const int* __restrict__ perm2,
                          int* __restrict__ orig3){
  int m = blockIdx.x*256 + threadIdx.x;
  if (m < N2) orig3[m] = perm1[perm2[m]];
}

// ---------------- layers 2/3 aggregation: compact list, paired float4 loads --
// wave per pooled dst m; 64 lanes = 2 edge-slots x 32 col-lanes (float4);
// 4 accumulator sets -> up to 4 loads in flight.
__global__ void k_aggHs(const int* __restrict__ orig, const int* __restrict__ map,
                        const float* __restrict__ hp,
                        const int* __restrict__ csr, const int* __restrict__ rowptr,
                        const int* __restrict__ deg, unsigned short* __restrict__ aggS,
                        int M){
  int cpx = gridDim.x >> 3;
  int bid = (int)((blockIdx.x & 7)*cpx + (blockIdx.x >> 3));
  int m = bid*4 + (threadIdx.x>>6);
  int lane = threadIdx.x & 63;
  if (m >= M) return;
  int d = orig[m];
  int rs = rowptr[d], dg = deg[d];
  int half = lane >> 5, cl = lane & 31;
  f32x4 acc[4];
  #pragma unroll
  for (int u=0;u<4;u++) acc[u] = (f32x4){0.f,0.f,0.f,0.f};
  for (int base=0; base<dg; base+=64){
    int e = base + lane;
    int ns = -1;
    if (e < dg){ int s = csr[rs+e]; ns = map[s]; }
    int cnt = min(64, dg-base);
    for (int jj=0; jj<cnt; jj+=8){
      #pragma unroll
      for (int u=0; u<4; u++){
        int ei = jj + u*2 + half;
        int nsj = __shfl(ns, ei & 63);
        if (ei < cnt && nsj >= 0){
          acc[u] += *(const f32x4*)(hp + (size_t)nsj*Hc + cl*4);
        }
      }
    }
  }
  f32x4 s4 = (acc[0]+acc[1]) + (acc[2]+acc[3]);
  #pragma unroll
  for (int i=0;i<4;i++) s4[i] += __shfl_xor(s4[i], 32);
  // redistribute: lane l writes cols 2l,2l+1 (live in lane l>>1, elems 2(l&1), 2(l&1)+1)
  float e0 = __shfl(s4[0], lane>>1);
  float e1 = __shfl(s4[1], lane>>1);
  float e2 = __shfl(s4[2], lane>>1);
  float e3 = __shfl(s4[3], lane>>1);
  float cx = (lane&1) ? e2 : e0;
  float cy = (lane&1) ? e3 : e1;
  unsigned short x0,x1,x2,y0,y1,y2;
  split3(cx, x0, x1, x2);
  split3(cy, y0, y1, y2);
  size_t fl = flIdx(m, 2*lane);
  *(unsigned*)&aggS[fl]        = (unsigned)x0 | ((unsigned)y0 << 16);
  *(unsigned*)&aggS[PL + fl]   = (unsigned)x1 | ((unsigned)y1 << 16);
  *(unsigned*)&aggS[2*PL + fl] = (unsigned)x2 | ((unsigned)y2 << 16);
}

// ---------------- conv2/conv3: 6-term split-bf16 MFMA GEMM -------------------
__launch_bounds__(256)
__global__ void k_convH(const unsigned short* __restrict__ A0s,
                        const unsigned short* __restrict__ A1s,
                        const unsigned short* __restrict__ Wsp,  // [p][3s][fl 16384]
                        const float* __restrict__ bias, float* __restrict__ hout, int M){
  int tid = threadIdx.x;
  int w = tid >> 6, l = tid & 63;
  int wm = w >> 1, wn = w & 1;
  int lr = l & 15, lk = l >> 4;
  int m0 = blockIdx.x * 64;

  f32x4 acc[2][4];
  #pragma unroll
  for (int mi=0;mi<2;mi++)
    #pragma unroll
    for (int ni=0;ni<4;ni++) acc[mi][ni] = (f32x4){0.f,0.f,0.f,0.f};

  #pragma unroll
  for (int kc=0; kc<4; kc++){
    #pragma unroll
    for (int p=0; p<2; p++){
      const unsigned short* As = p ? A1s : A0s;
      const unsigned short* Wp = Wsp + (size_t)p*3*16384;
      s16x8 af[3][2], bf[3][4];
      #pragma unroll
      for (int mi=0; mi<2; mi++){
        int tile = (m0 + wm*32 + mi*16) >> 4;
        size_t idx = (size_t)tile*2048 + (size_t)(kc*4+lk)*128 + (size_t)lr*8;
        af[0][mi] = *(const s16x8*)&As[idx];
        af[1][mi] = *(const s16x8*)&As[PL + idx];
        af[2][mi] = *(const s16x8*)&As[2*PL + idx];
      }
      #pragma unroll
      for (int ni=0; ni<4; ni++){
        int ct = wn*4 + ni;
        size_t idx = (size_t)ct*2048 + (size_t)(kc*4+lk)*128 + (size_t)lr*8;
        bf[0][ni] = *(const s16x8*)&Wp[idx];
        bf[1][ni] = *(const s16x8*)&Wp[16384 + idx];
        bf[2][ni] = *(const s16x8*)&Wp[32768 + idx];
      }
      #define TRM(sa,sb) \
        _Pragma("unroll") \
        for (int ni=0; ni<4; ni++){ \
          _Pragma("unroll") \
          for (int mi=0; mi<2; mi++){ \
            acc[mi][ni] = __builtin_amdgcn_mfma_f32_16x16x32_bf16(af[sa][mi], bf[sb][ni], acc[mi][ni], 0,0,0); \
          } \
        }
      TRM(0,0) TRM(0,1) TRM(1,0) TRM(1,1) TRM(0,2) TRM(2,0)
      #undef TRM
    }
  }

  #pragma unroll
  for (int mi=0; mi<2; mi++){
    #pragma unroll
    for (int reg=0; reg<4; reg++){
      int row = m0 + wm*32 + mi*16 + lk*4 + reg;
      if (row < M){
        #pragma unroll
        for (int ni=0; ni<4; ni++){
          int col = wn*64 + ni*16 + lr;
          hout[(size_t)row*Hc + col] = fmaxf(acc[mi][ni][reg] + bias[col], 0.f);
        }
      }
    }
  }
}

__global__ void k_compose(const int* __restrict__ map1, const int* __restrict__ newid2,
                          int* __restrict__ map2){
  int o = blockIdx.x*256 + threadIdx.x;
  if (o < N0){ int m = map1[o]; map2[o] = (m>=0) ? newid2[m] : -1; }
}

// ---------------- MLP head ---------------------------------------------------
__launch_bounds__(512)
__global__ void k_mlp(const float* __restrict__ z,
                      const float* __restrict__ Wl1T, const float* __restrict__ bl1,
                      const float* __restrict__ Wl2T, const float* __restrict__ bl2,
                      const float* __restrict__ Wl3, const float* __restrict__ bl3,
                      float* __restrict__ out){
  __shared__ float zs[256];
  __shared__ float u1[512];
  int g = blockIdx.x, t = threadIdx.x;
  if (t < 256) zs[t] = z[g*256 + t];
  __syncthreads();
  {
    float acc = bl1[t];
    #pragma unroll 8
    for (int f=0; f<256; f++) acc = fmaf(zs[f], Wl1T[f*512 + t], acc);
    u1[t] = fmaxf(acc, 0.f);
  }
  __syncthreads();
  if (t < 64){
    float acc = bl2[t];
    #pragma unroll 8
    for (int f=0; f<512; f++) acc = fmaf(u1[f], Wl2T[f*64 + t], acc);
    float v = fmaxf(acc, 0.f) * Wl3[t];
    for (int o=32;o>0;o>>=1) v += __shfl_xor(v, o);
    if (t == 0) out[g] = v + bl3[0];
  }
}

extern "C" void kernel_launch(void* const* d_in, const int* in_sizes, int n_in,
                              void* d_out, int out_size, void* d_ws, size_t ws_size,
                              hipStream_t stream){
  const float* x     = (const float*)d_in[0];
  const int*   esrc  = (const int*)d_in[1];
  const int*   edst  = (const int*)d_in[2];
  const float* Wrel1 = (const float*)d_in[5];
  const float* Wroot1= (const float*)d_in[6];
  const float* b1    = (const float*)d_in[7];
  const float* pw1   = (const float*)d_in[8];
  const float* Wrel2 = (const float*)d_in[9];
  const float* Wroot2= (const float*)d_in[10];
  const float* b2    = (const float*)d_in[11];
  const float* pw2   = (const float*)d_in[12];
  const float* Wrel3 = (const float*)d_in[13];
  const float* Wroot3= (const float*)d_in[14];
  const float* b3    = (const float*)d_in[15];
  const float* pw3   = (const float*)d_in[16];
  const float* Wl1   = (const float*)d_in[17];
  const float* bl1   = (const float*)d_in[18];
  const float* Wl2   = (const float*)d_in[19];
  const float* bl2   = (const float*)d_in[20];
  const float* Wl3   = (const float*)d_in[21];
  const float* bl3   = (const float*)d_in[22];
  float* out = (float*)d_out;

  char* ws = (char*)d_ws;
  size_t off = 0;
  auto alloc = [&](size_t elems)->void*{
    void* p = ws + off;
    off += ((elems*4 + 255)/256)*256;
    return p;
  };
  int*   deg    = (int*)alloc(N0);
  int*   rowptr = (int*)alloc(N0);
  int*   cursor = (int*)alloc(N0);
  int*   csr    = (int*)alloc(NE);
  int*   map1   = (int*)alloc(N0);
  int*   newid2 = (int*)alloc(N1);
  int*   map2   = (int*)alloc(N0);
  int*   perm1  = (int*)alloc(N1);
  int*   perm2  = (int*)alloc(N2);
  int*   perm3  = (int*)alloc(N3);
  int*   orig3  = (int*)alloc(N2);
  float* score1 = (float*)alloc(N0);
  float* score2 = (float*)alloc(N1);
  float* score3 = (float*)alloc(N2);
  float* agg1   = (float*)alloc((size_t)N0*FINc);
  float* WcatT  = (float*)alloc(22*Hc);
  float* Wl1T   = (float*)alloc(256*512);
  float* Wl2T   = (float*)alloc(512*64);
  unsigned short* Wsp = (unsigned short*)alloc(98304);  // 196608 bf16 = 98304 u32
  float* bigA   = (float*)alloc((size_t)N0*Hc);      // h1, then aggS (3 bf16 planes)
  float* hB     = (float*)alloc((size_t)N1*Hc);      // h2 -> h3
  float* hpA    = (float*)alloc((size_t)N1*Hc);      // hp1 -> hp2 -> hp3 (f32 row-major)
  unsigned short* hpS = (unsigned short*)alloc((size_t)3*N1*Hc/2);  // 3 bf16 planes, fragment layout
  float* z      = (float*)alloc(BG*256);

  float* h1   = bigA;
  unsigned short* aggS = (unsigned short*)bigA;   // 39.3 MB <= 52.4 MB, h1 dead by then
  float* h2   = hB;
  float* h3   = hB;

  hipMemsetAsync(deg, 0, N0*sizeof(int), stream);
  hipMemsetAsync(z,   0, BG*256*sizeof(float), stream);

  // CSR build + weight prep
  k_deg    <<<NE/256, 256, 0, stream>>>(edst, deg);
  k_rowptr <<<BG, NPGc, 0, stream>>>(deg, rowptr, cursor);
  k_scatter<<<NE/256, 256, 0, stream>>>(esrc, edst, cursor, csr);
  k_prep   <<<512, 256, 0, stream>>>(Wrel1, Wroot1, Wl1, Wl2, WcatT, Wl1T, Wl2T);
  k_prepw  <<<256, 256, 0, stream>>>(Wrel2, Wroot2, Wrel3, Wroot3, Wsp);

  // layer 1
  k_agg1  <<<N0/4, 256, 0, stream>>>(x, csr, rowptr, deg, agg1);
  k_conv1 <<<N0*32/256, 256, 0, stream>>>(x, agg1, WcatT, b1, h1);
  k_score <<<N0/4, 256, 0, stream>>>(h1, pw1, score1, N0);
  k_topk<NPGc, K1c, 512><<<BG, 512, 0, stream>>>(score1, map1, perm1);
  k_gather<<<N1/4, 256, 0, stream>>>(h1, score1, perm1, hpA, hpS, N1, 1);
  k_readout<<<BG, 512, 0, stream>>>(hpA, z, K1c);

  // layer 2
  k_aggHs <<<N1/4, 256, 0, stream>>>(perm1, map1, hpA, csr, rowptr, deg, aggS, N1);
  k_convH <<<N1/64, 256, 0, stream>>>(aggS, hpS, Wsp, b2, h2, N1);
  k_score <<<N1/4, 256, 0, stream>>>(h2, pw2, score2, N1);
  k_topk<K1c, K2c, 256><<<BG, 256, 0, stream>>>(score2, newid2, perm2);
  k_compose<<<N0/256, 256, 0, stream>>>(map1, newid2, map2);
  k_origmap<<<(N2+255)/256, 256, 0, stream>>>(perm1, perm2, orig3);
  k_gather<<<(N2+3)/4, 256, 0, stream>>>(h2, score2, perm2, hpA, hpS, N2, 1);
  k_readout<<<BG, 512, 0, stream>>>(hpA, z, K2c);

  // layer 3  (grid padded to x8 for bijective XCD swizzle)
  k_aggHs <<<10256, 256, 0, stream>>>(orig3, map2, hpA, csr, rowptr, deg, aggS, N2);
  k_convH <<<(N2+63)/64, 256, 0, stream>>>(aggS, hpS, Wsp + 98304, b3, h3, N2);
  k_score <<<(N2+3)/4, 256, 0, stream>>>(h3, pw3, score3, N2);
  k_topk<K2c, K3c, 256><<<BG, 256, 0, stream>>>(score3, newid2, perm3);
  k_gather<<<(N3+3)/4, 256, 0, stream>>>(h3, score3, perm3, hpA, hpS, N3, 0);
  k_readout<<<BG, 512, 0, stream>>>(hpA, z, K3c);

  // head
  k_mlp<<<BG, 512, 0, stream>>>(z, Wl1T, bl1, Wl2T, bl2, Wl3, bl3, out);
}

// Round 7
// 409.977 us; speedup vs baseline: 2.2129x; 1.1185x over previous
//
#include <hip/hip_runtime.h>
#include <math.h>

#define BG   200
#define NPGc 512
#define EPGc 8192
#define NE   (BG*EPGc)     // 1638400
#define N0   (BG*NPGc)     // 102400
#define FINc 11
#define Hc   128
#define K1c  256
#define K2c  205
#define K3c  164
#define N1   (BG*K1c)      // 51200
#define N2   (BG*K2c)      // 41000
#define N3   (BG*K3c)      // 32800

typedef float f32x4 __attribute__((ext_vector_type(4)));
typedef short s16x8 __attribute__((ext_vector_type(8)));

#define PL ((size_t)N1*Hc)      // hpS/aggS plane stride (elements)
#define PA ((size_t)N0*32)      // conv1 A-plane stride (elements)

// ---- 3-way RNE bf16 split: v = p0 + p1 + p2 + O(2^-24 |v|) -----------------
__device__ inline unsigned short bf16_rne(float v){
  unsigned u = __float_as_uint(v);
  unsigned r = u + 0x7FFFu + ((u >> 16) & 1u);
  return (unsigned short)(r >> 16);
}
__device__ inline float bf16_f32(unsigned short h){
  return __uint_as_float(((unsigned)h) << 16);
}
__device__ inline void split3(float v, unsigned short& r0, unsigned short& r1,
                              unsigned short& r2){
  r0 = bf16_rne(v); float v1 = v - bf16_f32(r0);
  r1 = bf16_rne(v1); float v2 = v1 - bf16_f32(r1);
  r2 = bf16_rne(v2);
}

// fragment-native layout, K=128: (row,k) -> [row>>4][k>>3][row&15][k&7]
__device__ inline size_t flIdx(int row, int k){
  return ((size_t)(row >> 4))*2048 + (size_t)(k >> 3)*128
       + (size_t)(row & 15)*8 + (size_t)(k & 7);
}
// same, K=32 (tile = 512 elems)
__device__ inline size_t flIdx32(int row, int k){
  return ((size_t)(row >> 4))*512 + (size_t)(k >> 3)*128
       + (size_t)(row & 15)*8 + (size_t)(k & 7);
}

// ---------------- CSR build --------------------------------------------------
__global__ void k_deg(const int* __restrict__ dst, int* __restrict__ deg){
  int e = blockIdx.x*256 + threadIdx.x;
  if (e < NE) atomicAdd(&deg[dst[e]], 1);
}

__global__ void k_rowptr(const int* __restrict__ deg, int* __restrict__ rowptr,
                         int* __restrict__ cursor){
  __shared__ int s[NPGc];
  int g = blockIdx.x, t = threadIdx.x;
  int d = deg[g*NPGc + t];
  s[t] = d;
  __syncthreads();
  for (int o=1;o<NPGc;o<<=1){
    int v = (t>=o) ? s[t-o] : 0;
    __syncthreads();
    s[t] += v;
    __syncthreads();
  }
  int rp = g*EPGc + s[t] - d;
  rowptr[g*NPGc+t] = rp;
  cursor[g*NPGc+t] = rp;
}

__global__ void k_scatter(const int* __restrict__ src, const int* __restrict__ dst,
                          int* __restrict__ cursor, int* __restrict__ csr){
  int e = blockIdx.x*256 + threadIdx.x;
  if (e < NE){
    int p = atomicAdd(&cursor[dst[e]], 1);
    csr[p] = src[e];
  }
}

// ---------------- weight prep ------------------------------------------------
__global__ void k_prep(const float* __restrict__ Wl1, const float* __restrict__ Wl2,
                       float* __restrict__ Wl1T, float* __restrict__ Wl2T){
  int idx = blockIdx.x*256 + threadIdx.x;
  if (idx < 256*512){
    int f = idx >> 9, t = idx & 511;
    Wl1T[idx] = Wl1[t*256 + f];
  }
  if (idx < 512*64){
    int f = idx >> 6, t = idx & 63;
    Wl2T[idx] = Wl2[t*512 + f];
  }
}

// split W2/W3 into 3 RNE bf16 planes, fragment-native (K=128).
__global__ void k_prepw(const float* __restrict__ Wrel2, const float* __restrict__ Wroot2,
                        const float* __restrict__ Wrel3, const float* __restrict__ Wroot3,
                        unsigned short* __restrict__ Wsp){
  int t = blockIdx.x*256 + threadIdx.x;   // 0..65535
  if (t >= 65536) return;
  int L = t >> 15, p = (t >> 14) & 1, ck = t & 16383;
  int c = ck >> 7, k = ck & 127;
  const float* W = L ? (p ? Wroot3 : Wrel3) : (p ? Wroot2 : Wrel2);
  unsigned short r0, r1, r2;
  split3(W[c*128 + k], r0, r1, r2);
  unsigned short* base = Wsp + (size_t)((L*2+p)*3)*16384;
  size_t fl = flIdx(c, k);
  base[fl]          = r0;
  base[16384 + fl]  = r1;
  base[32768 + fl]  = r2;
}

// conv1 weight: [128 cols][K=32: k<11 Wrel1, 11<=k<22 Wroot1, else 0], 3 planes.
__global__ void k_prepw1(const float* __restrict__ Wrel1, const float* __restrict__ Wroot1,
                         unsigned short* __restrict__ W1S){
  int t = blockIdx.x*256 + threadIdx.x;   // 0..4095
  if (t >= 4096) return;
  int c = t >> 5, k = t & 31;
  float v = (k < 11) ? Wrel1[c*11 + k] : (k < 22 ? Wroot1[c*11 + (k-11)] : 0.f);
  unsigned short r0, r1, r2;
  split3(v, r0, r1, r2);
  size_t fl = flIdx32(c, k);
  W1S[fl]        = r0;
  W1S[4096 + fl] = r1;
  W1S[8192 + fl] = r2;
}

// norms[l] = sqrt(sum pw_l^2)
__global__ void k_pwnorm(const float* __restrict__ pw1, const float* __restrict__ pw2,
                         const float* __restrict__ pw3, float* __restrict__ norms){
  __shared__ float s[384];
  int t = threadIdx.x;
  int which = t >> 7, idx = t & 127;
  float v = (which==0) ? pw1[idx] : (which==1 ? pw2[idx] : pw3[idx]);
  s[t] = v*v;
  __syncthreads();
  if (t < 3){
    float sum = 0.f;
    for (int i=0;i<128;i++) sum += s[t*128+i];
    norms[t] = sqrtf(sum);
  }
}

// ---------------- layer 1 aggregation: wave per dst, 4 edge-slots x 16 cols --
__global__ void k_agg1(const float* __restrict__ x, const int* __restrict__ csr,
                       const int* __restrict__ rowptr, const int* __restrict__ deg,
                       float* __restrict__ agg1){
  int bid = (int)((blockIdx.x & 7)*3200 + (blockIdx.x >> 3));  // XCD-contiguous
  int d = bid*4 + (threadIdx.x >> 6);
  if (d >= N0) return;
  int lane = threadIdx.x & 63;
  int slot = lane >> 4, f = lane & 15;
  int rs = rowptr[d], dg = deg[d];
  float a0 = 0.f, a1 = 0.f;
  for (int base=0; base<dg; base+=64){
    int e = base + lane;
    int s = 0;
    if (e < dg) s = csr[rs+e];
    int cnt = min(64, dg-base);
    for (int jj=0; jj<cnt; jj+=8){
      int s0 = __shfl(s, (jj + slot) & 63);
      int s1 = __shfl(s, (jj + 4 + slot) & 63);
      if (jj + slot < cnt && f < FINc)     a0 += x[s0*FINc + f];
      if (jj + 4 + slot < cnt && f < FINc) a1 += x[s1*FINc + f];
    }
  }
  a0 += a1;
  a0 += __shfl_xor(a0, 16);
  a0 += __shfl_xor(a0, 32);
  if (slot == 0 && f < FINc) agg1[d*FINc + f] = a0;
}

// build conv1 A-operand split planes: row n, k<11 agg1, k<22 x, else 0.
__global__ void k_splitA(const float* __restrict__ x, const float* __restrict__ agg1,
                         unsigned short* __restrict__ AS){
  int gid = blockIdx.x*256 + threadIdx.x;   // N0*16
  int row = gid >> 4, j = gid & 15;
  int k0 = j*2, k1 = k0 + 1;
  float v0 = (k0 < 11) ? agg1[row*11 + k0] : (k0 < 22 ? x[row*11 + (k0-11)] : 0.f);
  float v1 = (k1 < 11) ? agg1[row*11 + k1] : (k1 < 22 ? x[row*11 + (k1-11)] : 0.f);
  unsigned short a0,a1,a2,b0,b1,b2;
  split3(v0, a0, a1, a2);
  split3(v1, b0, b1, b2);
  size_t fl = flIdx32(row, k0);
  *(unsigned*)&AS[fl]        = (unsigned)a0 | ((unsigned)b0 << 16);
  *(unsigned*)&AS[PA + fl]   = (unsigned)a1 | ((unsigned)b1 << 16);
  *(unsigned*)&AS[2*PA + fl] = (unsigned)a2 | ((unsigned)b2 << 16);
}

// ---------------- conv1: 6-term split MFMA, K=32, fused score ---------------
__launch_bounds__(256)
__global__ void k_conv1m(const unsigned short* __restrict__ AS,
                         const unsigned short* __restrict__ W1S,
                         const float* __restrict__ bias, const float* __restrict__ pw,
                         const float* __restrict__ norm_p,
                         float* __restrict__ hout, float* __restrict__ score, int M){
  __shared__ float scds[64][2];
  int tid = threadIdx.x;
  int w = tid >> 6, l = tid & 63;
  int wm = w >> 1, wn = w & 1;
  int lr = l & 15, lk = l >> 4;
  int m0 = blockIdx.x * 64;

  f32x4 acc[2][4];
  #pragma unroll
  for (int mi=0;mi<2;mi++)
    #pragma unroll
    for (int ni=0;ni<4;ni++) acc[mi][ni] = (f32x4){0.f,0.f,0.f,0.f};

  s16x8 af[3][2], bf[3][4];
  #pragma unroll
  for (int mi=0; mi<2; mi++){
    int tile = (m0 + wm*32 + mi*16) >> 4;
    size_t idx = (size_t)tile*512 + (size_t)lk*128 + (size_t)lr*8;
    af[0][mi] = *(const s16x8*)&AS[idx];
    af[1][mi] = *(const s16x8*)&AS[PA + idx];
    af[2][mi] = *(const s16x8*)&AS[2*PA + idx];
  }
  #pragma unroll
  for (int ni=0; ni<4; ni++){
    int ct = wn*4 + ni;
    size_t idx = (size_t)ct*512 + (size_t)lk*128 + (size_t)lr*8;
    bf[0][ni] = *(const s16x8*)&W1S[idx];
    bf[1][ni] = *(const s16x8*)&W1S[4096 + idx];
    bf[2][ni] = *(const s16x8*)&W1S[8192 + idx];
  }
  #define TRM(sa,sb) \
    _Pragma("unroll") \
    for (int ni=0; ni<4; ni++){ \
      _Pragma("unroll") \
      for (int mi=0; mi<2; mi++){ \
        acc[mi][ni] = __builtin_amdgcn_mfma_f32_16x16x32_bf16(af[sa][mi], bf[sb][ni], acc[mi][ni], 0,0,0); \
      } \
    }
  TRM(0,0) TRM(0,1) TRM(1,0) TRM(1,1) TRM(0,2) TRM(2,0)
  #undef TRM

  float nrm = *norm_p;
  float pwv[4], biasv[4];
  #pragma unroll
  for (int ni=0;ni<4;ni++){
    int col = wn*64 + ni*16 + lr;
    pwv[ni] = pw[col]; biasv[ni] = bias[col];
  }
  #pragma unroll
  for (int mi=0; mi<2; mi++){
    #pragma unroll
    for (int reg=0; reg<4; reg++){
      int rl = wm*32 + mi*16 + lk*4 + reg;
      int row = m0 + rl;
      float hv[4]; float sc = 0.f;
      #pragma unroll
      for (int ni=0; ni<4; ni++){
        hv[ni] = fmaxf(acc[mi][ni][reg] + biasv[ni], 0.f);
        sc += hv[ni]*pwv[ni];
      }
      if (row < M){
        #pragma unroll
        for (int ni=0; ni<4; ni++)
          hout[(size_t)row*Hc + wn*64 + ni*16 + lr] = hv[ni];
      }
      sc += __shfl_xor(sc,1); sc += __shfl_xor(sc,2);
      sc += __shfl_xor(sc,4); sc += __shfl_xor(sc,8);
      if (lr == 0) scds[rl][wn] = sc;
    }
  }
  __syncthreads();
  if (tid < 64){
    int row = m0 + tid;
    if (row < M) score[row] = tanhf((scds[tid][0] + scds[tid][1]) / nrm);
  }
}

// ---------------- per-graph top-k via bitonic sort (val desc, idx asc) -------
template<int N, int K, int NP2>
__global__ void k_topk(const float* __restrict__ score, int* __restrict__ newid,
                       int* __restrict__ perm){
  __shared__ float sv[NP2];
  __shared__ int   si[NP2];
  int g = blockIdx.x, t = threadIdx.x;
  sv[t] = (t < N) ? score[g*N + t] : -INFINITY;
  si[t] = t;
  __syncthreads();
  for (int k=2;k<=NP2;k<<=1){
    for (int j=k>>1;j>0;j>>=1){
      int p = t ^ j;
      if (p > t){
        float va = sv[t], vb = sv[p];
        int   ia = si[t], ib = si[p];
        bool good = (va > vb) || (va == vb && ia < ib);
        bool up   = ((t & k) == 0);
        if (good != up){ sv[t]=vb; si[t]=ib; sv[p]=va; si[p]=ia; }
      }
      __syncthreads();
    }
  }
  if (t < N) newid[g*N + t] = -1;
  __syncthreads();
  if (t < K){
    int old = si[t];
    newid[g*N + old] = g*K + t;
    perm[g*K + t]    = g*N + old;
  }
}

// hp[m] = h[perm[m]]*score[perm[m]]; also emit pre-split fragment planes hpS
__global__ void k_gather(const float* __restrict__ h, const float* __restrict__ score,
                         const int* __restrict__ perm, float* __restrict__ hp,
                         unsigned short* __restrict__ hpS, int M, int doSplit){
  int m = blockIdx.x*4 + (threadIdx.x>>6);
  int l = threadIdx.x & 63;
  if (m >= M) return;
  int p = perm[m];
  float s = score[p];
  float2 v = ((const float2*)(h + (size_t)p*Hc))[l];
  v.x *= s; v.y *= s;
  ((float2*)(hp + (size_t)m*Hc))[l] = v;
  if (doSplit){
    unsigned short x0,x1,x2,y0,y1,y2;
    split3(v.x, x0, x1, x2);
    split3(v.y, y0, y1, y2);
    size_t fl = flIdx(m, 2*l);
    *(unsigned*)&hpS[fl]        = (unsigned)x0 | ((unsigned)y0 << 16);
    *(unsigned*)&hpS[PL + fl]   = (unsigned)x1 | ((unsigned)y1 << 16);
    *(unsigned*)&hpS[2*PL + fl] = (unsigned)x2 | ((unsigned)y2 << 16);
  }
}

__global__ void k_readout(const float* __restrict__ hp, float* __restrict__ z, int k){
  __shared__ float smx[4][Hc];
  __shared__ float ssm[4][Hc];
  int g = blockIdx.x;
  int rc = threadIdx.x >> 7, j = threadIdx.x & 127;
  float mx = -INFINITY, sm = 0.f;
  const float* base = hp + (size_t)g*k*Hc + j;
  for (int r=rc; r<k; r+=4){
    float v = base[(size_t)r*Hc];
    mx = fmaxf(mx, v); sm += v;
  }
  smx[rc][j] = mx; ssm[rc][j] = sm;
  __syncthreads();
  if (rc == 0){
    mx = fmaxf(fmaxf(smx[0][j], smx[1][j]), fmaxf(smx[2][j], smx[3][j]));
    sm = ssm[0][j] + ssm[1][j] + ssm[2][j] + ssm[3][j];
    z[g*256 + j]       += mx;
    z[g*256 + 128 + j] += sm / (float)k;
  }
}

// orig3[m] = perm1[perm2[m]]
__global__ void k_origmap(const int* __restrict__ perm1, const int* __restrict__ perm2,
                          int* __restrict__ orig3){
  int m = blockIdx.x*256 + threadIdx.x;
  if (m < N2) orig3[m] = perm1[perm2[m]];
}

// ---------------- layers 2/3 aggregation: compact list, paired float4 loads --
__global__ void k_aggHs(const int* __restrict__ orig, const int* __restrict__ map,
                        const float* __restrict__ hp,
                        const int* __restrict__ csr, const int* __restrict__ rowptr,
                        const int* __restrict__ deg, unsigned short* __restrict__ aggS,
                        int M){
  int cpx = gridDim.x >> 3;
  int bid = (int)((blockIdx.x & 7)*cpx + (blockIdx.x >> 3));
  int m = bid*4 + (threadIdx.x>>6);
  int lane = threadIdx.x & 63;
  if (m >= M) return;
  int d = orig[m];
  int rs = rowptr[d], dg = deg[d];
  int half = lane >> 5, cl = lane & 31;
  f32x4 acc[4];
  #pragma unroll
  for (int u=0;u<4;u++) acc[u] = (f32x4){0.f,0.f,0.f,0.f};
  for (int base=0; base<dg; base+=64){
    int e = base + lane;
    int ns = -1;
    if (e < dg){ int s = csr[rs+e]; ns = map[s]; }
    int cnt = min(64, dg-base);
    for (int jj=0; jj<cnt; jj+=8){
      #pragma unroll
      for (int u=0; u<4; u++){
        int ei = jj + u*2 + half;
        int nsj = __shfl(ns, ei & 63);
        if (ei < cnt && nsj >= 0){
          acc[u] += *(const f32x4*)(hp + (size_t)nsj*Hc + cl*4);
        }
      }
    }
  }
  f32x4 s4 = (acc[0]+acc[1]) + (acc[2]+acc[3]);
  #pragma unroll
  for (int i=0;i<4;i++) s4[i] += __shfl_xor(s4[i], 32);
  float e0 = __shfl(s4[0], lane>>1);
  float e1 = __shfl(s4[1], lane>>1);
  float e2 = __shfl(s4[2], lane>>1);
  float e3 = __shfl(s4[3], lane>>1);
  float cx = (lane&1) ? e2 : e0;
  float cy = (lane&1) ? e3 : e1;
  unsigned short x0,x1,x2,y0,y1,y2;
  split3(cx, x0, x1, x2);
  split3(cy, y0, y1, y2);
  size_t fl = flIdx(m, 2*lane);
  *(unsigned*)&aggS[fl]        = (unsigned)x0 | ((unsigned)y0 << 16);
  *(unsigned*)&aggS[PL + fl]   = (unsigned)x1 | ((unsigned)y1 << 16);
  *(unsigned*)&aggS[2*PL + fl] = (unsigned)x2 | ((unsigned)y2 << 16);
}

// ---------------- conv2/conv3: 6-term split MFMA, fused score ----------------
__launch_bounds__(256)
__global__ void k_convH(const unsigned short* __restrict__ A0s,
                        const unsigned short* __restrict__ A1s,
                        const unsigned short* __restrict__ Wsp,  // [p][3s][fl 16384]
                        const float* __restrict__ bias, const float* __restrict__ pw,
                        const float* __restrict__ norm_p,
                        float* __restrict__ hout, float* __restrict__ score, int M){
  __shared__ float scds[64][2];
  int tid = threadIdx.x;
  int w = tid >> 6, l = tid & 63;
  int wm = w >> 1, wn = w & 1;
  int lr = l & 15, lk = l >> 4;
  int m0 = blockIdx.x * 64;

  f32x4 acc[2][4];
  #pragma unroll
  for (int mi=0;mi<2;mi++)
    #pragma unroll
    for (int ni=0;ni<4;ni++) acc[mi][ni] = (f32x4){0.f,0.f,0.f,0.f};

  #pragma unroll
  for (int kc=0; kc<4; kc++){
    #pragma unroll
    for (int p=0; p<2; p++){
      const unsigned short* As = p ? A1s : A0s;
      const unsigned short* Wp = Wsp + (size_t)p*3*16384;
      s16x8 af[3][2], bf[3][4];
      #pragma unroll
      for (int mi=0; mi<2; mi++){
        int tile = (m0 + wm*32 + mi*16) >> 4;
        size_t idx = (size_t)tile*2048 + (size_t)(kc*4+lk)*128 + (size_t)lr*8;
        af[0][mi] = *(const s16x8*)&As[idx];
        af[1][mi] = *(const s16x8*)&As[PL + idx];
        af[2][mi] = *(const s16x8*)&As[2*PL + idx];
      }
      #pragma unroll
      for (int ni=0; ni<4; ni++){
        int ct = wn*4 + ni;
        size_t idx = (size_t)ct*2048 + (size_t)(kc*4+lk)*128 + (size_t)lr*8;
        bf[0][ni] = *(const s16x8*)&Wp[idx];
        bf[1][ni] = *(const s16x8*)&Wp[16384 + idx];
        bf[2][ni] = *(const s16x8*)&Wp[32768 + idx];
      }
      #define TRM(sa,sb) \
        _Pragma("unroll") \
        for (int ni=0; ni<4; ni++){ \
          _Pragma("unroll") \
          for (int mi=0; mi<2; mi++){ \
            acc[mi][ni] = __builtin_amdgcn_mfma_f32_16x16x32_bf16(af[sa][mi], bf[sb][ni], acc[mi][ni], 0,0,0); \
          } \
        }
      TRM(0,0) TRM(0,1) TRM(1,0) TRM(1,1) TRM(0,2) TRM(2,0)
      #undef TRM
    }
  }

  float nrm = *norm_p;
  float pwv[4], biasv[4];
  #pragma unroll
  for (int ni=0;ni<4;ni++){
    int col = wn*64 + ni*16 + lr;
    pwv[ni] = pw[col]; biasv[ni] = bias[col];
  }
  #pragma unroll
  for (int mi=0; mi<2; mi++){
    #pragma unroll
    for (int reg=0; reg<4; reg++){
      int rl = wm*32 + mi*16 + lk*4 + reg;
      int row = m0 + rl;
      float hv[4]; float sc = 0.f;
      #pragma unroll
      for (int ni=0; ni<4; ni++){
        hv[ni] = fmaxf(acc[mi][ni][reg] + biasv[ni], 0.f);
        sc += hv[ni]*pwv[ni];
      }
      if (row < M){
        #pragma unroll
        for (int ni=0; ni<4; ni++)
          hout[(size_t)row*Hc + wn*64 + ni*16 + lr] = hv[ni];
      }
      sc += __shfl_xor(sc,1); sc += __shfl_xor(sc,2);
      sc += __shfl_xor(sc,4); sc += __shfl_xor(sc,8);
      if (lr == 0) scds[rl][wn] = sc;
    }
  }
  __syncthreads();
  if (tid < 64){
    int row = m0 + tid;
    if (row < M) score[row] = tanhf((scds[tid][0] + scds[tid][1]) / nrm);
  }
}

__global__ void k_compose(const int* __restrict__ map1, const int* __restrict__ newid2,
                          int* __restrict__ map2){
  int o = blockIdx.x*256 + threadIdx.x;
  if (o < N0){ int m = map1[o]; map2[o] = (m>=0) ? newid2[m] : -1; }
}

// ---------------- MLP head ---------------------------------------------------
__launch_bounds__(512)
__global__ void k_mlp(const float* __restrict__ z,
                      const float* __restrict__ Wl1T, const float* __restrict__ bl1,
                      const float* __restrict__ Wl2T, const float* __restrict__ bl2,
                      const float* __restrict__ Wl3, const float* __restrict__ bl3,
                      float* __restrict__ out){
  __shared__ float zs[256];
  __shared__ float u1[512];
  int g = blockIdx.x, t = threadIdx.x;
  if (t < 256) zs[t] = z[g*256 + t];
  __syncthreads();
  {
    float acc = bl1[t];
    #pragma unroll 8
    for (int f=0; f<256; f++) acc = fmaf(zs[f], Wl1T[f*512 + t], acc);
    u1[t] = fmaxf(acc, 0.f);
  }
  __syncthreads();
  if (t < 64){
    float acc = bl2[t];
    #pragma unroll 8
    for (int f=0; f<512; f++) acc = fmaf(u1[f], Wl2T[f*64 + t], acc);
    float v = fmaxf(acc, 0.f) * Wl3[t];
    for (int o=32;o>0;o>>=1) v += __shfl_xor(v, o);
    if (t == 0) out[g] = v + bl3[0];
  }
}

extern "C" void kernel_launch(void* const* d_in, const int* in_sizes, int n_in,
                              void* d_out, int out_size, void* d_ws, size_t ws_size,
                              hipStream_t stream){
  const float* x     = (const float*)d_in[0];
  const int*   esrc  = (const int*)d_in[1];
  const int*   edst  = (const int*)d_in[2];
  const float* Wrel1 = (const float*)d_in[5];
  const float* Wroot1= (const float*)d_in[6];
  const float* b1    = (const float*)d_in[7];
  const float* pw1   = (const float*)d_in[8];
  const float* Wrel2 = (const float*)d_in[9];
  const float* Wroot2= (const float*)d_in[10];
  const float* b2    = (const float*)d_in[11];
  const float* pw2   = (const float*)d_in[12];
  const float* Wrel3 = (const float*)d_in[13];
  const float* Wroot3= (const float*)d_in[14];
  const float* b3    = (const float*)d_in[15];
  const float* pw3   = (const float*)d_in[16];
  const float* Wl1   = (const float*)d_in[17];
  const float* bl1   = (const float*)d_in[18];
  const float* Wl2   = (const float*)d_in[19];
  const float* bl2   = (const float*)d_in[20];
  const float* Wl3   = (const float*)d_in[21];
  const float* bl3   = (const float*)d_in[22];
  float* out = (float*)d_out;

  char* ws = (char*)d_ws;
  size_t off = 0;
  auto alloc = [&](size_t elems)->void*{
    void* p = ws + off;
    off += ((elems*4 + 255)/256)*256;
    return p;
  };
  int*   deg    = (int*)alloc(N0);
  int*   rowptr = (int*)alloc(N0);
  int*   cursor = (int*)alloc(N0);
  int*   csr    = (int*)alloc(NE);
  int*   map1   = (int*)alloc(N0);
  int*   newid2 = (int*)alloc(N1);
  int*   map2   = (int*)alloc(N0);
  int*   perm1  = (int*)alloc(N1);
  int*   perm2  = (int*)alloc(N2);
  int*   perm3  = (int*)alloc(N3);
  int*   orig3  = (int*)alloc(N2);
  float* score1 = (float*)alloc(N0);
  float* score2 = (float*)alloc(N1);
  float* score3 = (float*)alloc(N2);
  float* agg1   = (float*)alloc((size_t)N0*FINc);
  float* Wl1T   = (float*)alloc(256*512);
  float* Wl2T   = (float*)alloc(512*64);
  unsigned short* Wsp = (unsigned short*)alloc(98304);   // 196608 bf16
  unsigned short* W1S = (unsigned short*)alloc(6144);    // 12288 bf16
  float* norms  = (float*)alloc(3);
  float* bigA   = (float*)alloc((size_t)N0*Hc);      // h1, then aggS (3 planes)
  float* hB     = (float*)alloc((size_t)N1*Hc);      // h2 -> h3
  float* hpA    = (float*)alloc((size_t)N1*Hc);      // hp f32 row-major
  unsigned short* hpS = (unsigned short*)alloc((size_t)3*N1*Hc/2);  // 3 planes, frag layout
  float* z      = (float*)alloc(BG*256);

  float* h1   = bigA;
  unsigned short* aggS = (unsigned short*)bigA;   // 39.3 MB <= 52.4 MB, h1 dead by then
  unsigned short* a1S  = hpS;                     // 19.7 MB, dead before gather fills hpS
  float* h2   = hB;
  float* h3   = hB;

  hipMemsetAsync(deg, 0, N0*sizeof(int), stream);
  hipMemsetAsync(z,   0, BG*256*sizeof(float), stream);

  // CSR build + weight prep
  k_deg    <<<NE/256, 256, 0, stream>>>(edst, deg);
  k_rowptr <<<BG, NPGc, 0, stream>>>(deg, rowptr, cursor);
  k_scatter<<<NE/256, 256, 0, stream>>>(esrc, edst, cursor, csr);
  k_prep   <<<512, 256, 0, stream>>>(Wl1, Wl2, Wl1T, Wl2T);
  k_prepw  <<<256, 256, 0, stream>>>(Wrel2, Wroot2, Wrel3, Wroot3, Wsp);
  k_prepw1 <<<16, 256, 0, stream>>>(Wrel1, Wroot1, W1S);
  k_pwnorm <<<1, 384, 0, stream>>>(pw1, pw2, pw3, norms);

  // layer 1
  k_agg1  <<<N0/4, 256, 0, stream>>>(x, csr, rowptr, deg, agg1);
  k_splitA<<<N0*16/256, 256, 0, stream>>>(x, agg1, a1S);
  k_conv1m<<<N0/64, 256, 0, stream>>>(a1S, W1S, b1, pw1, norms+0, h1, score1, N0);
  k_topk<NPGc, K1c, 512><<<BG, 512, 0, stream>>>(score1, map1, perm1);
  k_gather<<<N1/4, 256, 0, stream>>>(h1, score1, perm1, hpA, hpS, N1, 1);
  k_readout<<<BG, 512, 0, stream>>>(hpA, z, K1c);

  // layer 2
  k_aggHs <<<N1/4, 256, 0, stream>>>(perm1, map1, hpA, csr, rowptr, deg, aggS, N1);
  k_convH <<<N1/64, 256, 0, stream>>>(aggS, hpS, Wsp, b2, pw2, norms+1, h2, score2, N1);
  k_topk<K1c, K2c, 256><<<BG, 256, 0, stream>>>(score2, newid2, perm2);
  k_compose<<<N0/256, 256, 0, stream>>>(map1, newid2, map2);
  k_origmap<<<(N2+255)/256, 256, 0, stream>>>(perm1, perm2, orig3);
  k_gather<<<(N2+3)/4, 256, 0, stream>>>(h2, score2, perm2, hpA, hpS, N2, 1);
  k_readout<<<BG, 512, 0, stream>>>(hpA, z, K2c);

  // layer 3  (grid padded to x8 for bijective XCD swizzle)
  k_aggHs <<<10256, 256, 0, stream>>>(orig3, map2, hpA, csr, rowptr, deg, aggS, N2);
  k_convH <<<(N2+63)/64, 256, 0, stream>>>(aggS, hpS, Wsp + 98304, b3, pw3, norms+2, h3, score3, N2);
  k_topk<K2c, K3c, 256><<<BG, 256, 0, stream>>>(score3, newid2, perm3);
  k_gather<<<(N3+3)/4, 256, 0, stream>>>(h3, score3, perm3, hpA, hpS, N3, 0);
  k_readout<<<BG, 512, 0, stream>>>(hpA, z, K3c);

  // head
  k_mlp<<<BG, 512, 0, stream>>>(z, Wl1T, bl1, Wl2T, bl2, Wl3, bl3, out);
}

// Round 8
// 323.045 us; speedup vs baseline: 2.8085x; 1.2691x over previous
//
#include <hip/hip_runtime.h>
#include <math.h>

#define BG   200
#define NPGc 512
#define EPGc 8192
#define NE   (BG*EPGc)     // 1638400
#define N0   (BG*NPGc)     // 102400
#define FINc 11
#define Hc   128
#define K1c  256
#define K2c  205
#define K3c  164
#define N1   (BG*K1c)      // 51200
#define N2   (BG*K2c)      // 41000
#define N3   (BG*K3c)      // 32800

typedef float f32x4 __attribute__((ext_vector_type(4)));
typedef short s16x8 __attribute__((ext_vector_type(8)));

#define PL ((size_t)N1*Hc)      // hpS/aggS plane stride (elements)
#define PA ((size_t)N0*32)      // conv1 A-plane stride (elements)

// ---- 3-way RNE bf16 split: v = p0 + p1 + p2 + O(2^-24 |v|) -----------------
__device__ inline unsigned short bf16_rne(float v){
  unsigned u = __float_as_uint(v);
  unsigned r = u + 0x7FFFu + ((u >> 16) & 1u);
  return (unsigned short)(r >> 16);
}
__device__ inline float bf16_f32(unsigned short h){
  return __uint_as_float(((unsigned)h) << 16);
}
__device__ inline void split3(float v, unsigned short& r0, unsigned short& r1,
                              unsigned short& r2){
  r0 = bf16_rne(v); float v1 = v - bf16_f32(r0);
  r1 = bf16_rne(v1); float v2 = v1 - bf16_f32(r1);
  r2 = bf16_rne(v2);
}

// fragment-native layout, K=128: (row,k) -> [row>>4][k>>3][row&15][k&7]
__device__ inline size_t flIdx(int row, int k){
  return ((size_t)(row >> 4))*2048 + (size_t)(k >> 3)*128
       + (size_t)(row & 15)*8 + (size_t)(k & 7);
}
// same, K=32 (tile = 512 elems)
__device__ inline size_t flIdx32(int row, int k){
  return ((size_t)(row >> 4))*512 + (size_t)(k >> 3)*128
       + (size_t)(row & 15)*8 + (size_t)(k & 7);
}

// ---------------- CSR build: block-per-graph counting sort -------------------
// All csr writes for a graph stay in one CU/XCD -> each HBM line written once.
__launch_bounds__(512)
__global__ void k_csr(const int* __restrict__ esrc, const int* __restrict__ edst,
                      int* __restrict__ deg, int* __restrict__ rowptr,
                      int* __restrict__ csr){
  __shared__ int ed[EPGc];    // 32 KB: local dst per edge
  __shared__ int cnt[NPGc];
  __shared__ int sc[NPGc];
  int g = blockIdx.x, t = threadIdx.x;
  cnt[t] = 0;
  __syncthreads();
  int gb = g*EPGc;
  for (int i=t; i<EPGc; i+=512){
    int dl = edst[gb+i] & (NPGc-1);   // dst = g*512 + r
    ed[i] = dl;
    atomicAdd(&cnt[dl], 1);
  }
  __syncthreads();
  int d = cnt[t];
  sc[t] = d;
  __syncthreads();
  for (int o=1;o<NPGc;o<<=1){
    int v = (t>=o) ? sc[t-o] : 0;
    __syncthreads();
    sc[t] += v;
    __syncthreads();
  }
  deg[g*NPGc+t]    = d;
  rowptr[g*NPGc+t] = gb + sc[t] - d;
  cnt[t] = sc[t] - d;                 // reuse as local cursor
  __syncthreads();
  for (int i=t; i<EPGc; i+=512){
    int p = atomicAdd(&cnt[ed[i]], 1);
    csr[gb+p] = esrc[gb+i];
  }
}

// ---------------- weight prep ------------------------------------------------
__global__ void k_prep(const float* __restrict__ Wl1, const float* __restrict__ Wl2,
                       float* __restrict__ Wl1T, float* __restrict__ Wl2T){
  int idx = blockIdx.x*256 + threadIdx.x;
  if (idx < 256*512){
    int f = idx >> 9, t = idx & 511;
    Wl1T[idx] = Wl1[t*256 + f];
  }
  if (idx < 512*64){
    int f = idx >> 6, t = idx & 63;
    Wl2T[idx] = Wl2[t*512 + f];
  }
}

__global__ void k_prepw(const float* __restrict__ Wrel2, const float* __restrict__ Wroot2,
                        const float* __restrict__ Wrel3, const float* __restrict__ Wroot3,
                        unsigned short* __restrict__ Wsp){
  int t = blockIdx.x*256 + threadIdx.x;   // 0..65535
  if (t >= 65536) return;
  int L = t >> 15, p = (t >> 14) & 1, ck = t & 16383;
  int c = ck >> 7, k = ck & 127;
  const float* W = L ? (p ? Wroot3 : Wrel3) : (p ? Wroot2 : Wrel2);
  unsigned short r0, r1, r2;
  split3(W[c*128 + k], r0, r1, r2);
  unsigned short* base = Wsp + (size_t)((L*2+p)*3)*16384;
  size_t fl = flIdx(c, k);
  base[fl]          = r0;
  base[16384 + fl]  = r1;
  base[32768 + fl]  = r2;
}

__global__ void k_prepw1(const float* __restrict__ Wrel1, const float* __restrict__ Wroot1,
                         unsigned short* __restrict__ W1S){
  int t = blockIdx.x*256 + threadIdx.x;   // 0..4095
  if (t >= 4096) return;
  int c = t >> 5, k = t & 31;
  float v = (k < 11) ? Wrel1[c*11 + k] : (k < 22 ? Wroot1[c*11 + (k-11)] : 0.f);
  unsigned short r0, r1, r2;
  split3(v, r0, r1, r2);
  size_t fl = flIdx32(c, k);
  W1S[fl]        = r0;
  W1S[4096 + fl] = r1;
  W1S[8192 + fl] = r2;
}

__global__ void k_pwnorm(const float* __restrict__ pw1, const float* __restrict__ pw2,
                         const float* __restrict__ pw3, float* __restrict__ norms){
  __shared__ float s[384];
  int t = threadIdx.x;
  int which = t >> 7, idx = t & 127;
  float v = (which==0) ? pw1[idx] : (which==1 ? pw2[idx] : pw3[idx]);
  s[t] = v*v;
  __syncthreads();
  if (t < 3){
    float sum = 0.f;
    for (int i=0;i<128;i++) sum += s[t*128+i];
    norms[t] = sqrtf(sum);
  }
}

// ---------------- layer 1 aggregation: wave per dst, 4 edge-slots x 16 cols --
__global__ void k_agg1(const float* __restrict__ x, const int* __restrict__ csr,
                       const int* __restrict__ rowptr, const int* __restrict__ deg,
                       float* __restrict__ agg1){
  int bid = (int)((blockIdx.x & 7)*3200 + (blockIdx.x >> 3));  // XCD-contiguous
  int d = bid*4 + (threadIdx.x >> 6);
  if (d >= N0) return;
  int lane = threadIdx.x & 63;
  int slot = lane >> 4, f = lane & 15;
  int rs = rowptr[d], dg = deg[d];
  float a0 = 0.f, a1 = 0.f;
  for (int base=0; base<dg; base+=64){
    int e = base + lane;
    int s = 0;
    if (e < dg) s = csr[rs+e];
    int cnt = min(64, dg-base);
    for (int jj=0; jj<cnt; jj+=8){
      int s0 = __shfl(s, (jj + slot) & 63);
      int s1 = __shfl(s, (jj + 4 + slot) & 63);
      if (jj + slot < cnt && f < FINc)     a0 += x[s0*FINc + f];
      if (jj + 4 + slot < cnt && f < FINc) a1 += x[s1*FINc + f];
    }
  }
  a0 += a1;
  a0 += __shfl_xor(a0, 16);
  a0 += __shfl_xor(a0, 32);
  if (slot == 0 && f < FINc) agg1[d*FINc + f] = a0;
}

// build conv1 A-operand split planes
__global__ void k_splitA(const float* __restrict__ x, const float* __restrict__ agg1,
                         unsigned short* __restrict__ AS){
  int gid = blockIdx.x*256 + threadIdx.x;   // N0*16
  int row = gid >> 4, j = gid & 15;
  int k0 = j*2, k1 = k0 + 1;
  float v0 = (k0 < 11) ? agg1[row*11 + k0] : (k0 < 22 ? x[row*11 + (k0-11)] : 0.f);
  float v1 = (k1 < 11) ? agg1[row*11 + k1] : (k1 < 22 ? x[row*11 + (k1-11)] : 0.f);
  unsigned short a0,a1,a2,b0,b1,b2;
  split3(v0, a0, a1, a2);
  split3(v1, b0, b1, b2);
  size_t fl = flIdx32(row, k0);
  *(unsigned*)&AS[fl]        = (unsigned)a0 | ((unsigned)b0 << 16);
  *(unsigned*)&AS[PA + fl]   = (unsigned)a1 | ((unsigned)b1 << 16);
  *(unsigned*)&AS[2*PA + fl] = (unsigned)a2 | ((unsigned)b2 << 16);
}

// ---------------- conv1: 6-term split MFMA, K=32, fused score ---------------
__launch_bounds__(256)
__global__ void k_conv1m(const unsigned short* __restrict__ AS,
                         const unsigned short* __restrict__ W1S,
                         const float* __restrict__ bias, const float* __restrict__ pw,
                         const float* __restrict__ norm_p,
                         float* __restrict__ hout, float* __restrict__ score, int M){
  __shared__ float scds[64][2];
  int tid = threadIdx.x;
  int w = tid >> 6, l = tid & 63;
  int wm = w >> 1, wn = w & 1;
  int lr = l & 15, lk = l >> 4;
  int m0 = blockIdx.x * 64;

  f32x4 acc[2][4];
  #pragma unroll
  for (int mi=0;mi<2;mi++)
    #pragma unroll
    for (int ni=0;ni<4;ni++) acc[mi][ni] = (f32x4){0.f,0.f,0.f,0.f};

  s16x8 af[3][2], bf[3][4];
  #pragma unroll
  for (int mi=0; mi<2; mi++){
    int tile = (m0 + wm*32 + mi*16) >> 4;
    size_t idx = (size_t)tile*512 + (size_t)lk*128 + (size_t)lr*8;
    af[0][mi] = *(const s16x8*)&AS[idx];
    af[1][mi] = *(const s16x8*)&AS[PA + idx];
    af[2][mi] = *(const s16x8*)&AS[2*PA + idx];
  }
  #pragma unroll
  for (int ni=0; ni<4; ni++){
    int ct = wn*4 + ni;
    size_t idx = (size_t)ct*512 + (size_t)lk*128 + (size_t)lr*8;
    bf[0][ni] = *(const s16x8*)&W1S[idx];
    bf[1][ni] = *(const s16x8*)&W1S[4096 + idx];
    bf[2][ni] = *(const s16x8*)&W1S[8192 + idx];
  }
  #define TRM(sa,sb) \
    _Pragma("unroll") \
    for (int ni=0; ni<4; ni++){ \
      _Pragma("unroll") \
      for (int mi=0; mi<2; mi++){ \
        acc[mi][ni] = __builtin_amdgcn_mfma_f32_16x16x32_bf16(af[sa][mi], bf[sb][ni], acc[mi][ni], 0,0,0); \
      } \
    }
  TRM(0,0) TRM(0,1) TRM(1,0) TRM(1,1) TRM(0,2) TRM(2,0)
  #undef TRM

  float nrm = *norm_p;
  float pwv[4], biasv[4];
  #pragma unroll
  for (int ni=0;ni<4;ni++){
    int col = wn*64 + ni*16 + lr;
    pwv[ni] = pw[col]; biasv[ni] = bias[col];
  }
  #pragma unroll
  for (int mi=0; mi<2; mi++){
    #pragma unroll
    for (int reg=0; reg<4; reg++){
      int rl = wm*32 + mi*16 + lk*4 + reg;
      int row = m0 + rl;
      float hv[4]; float sc = 0.f;
      #pragma unroll
      for (int ni=0; ni<4; ni++){
        hv[ni] = fmaxf(acc[mi][ni][reg] + biasv[ni], 0.f);
        sc += hv[ni]*pwv[ni];
      }
      if (row < M){
        #pragma unroll
        for (int ni=0; ni<4; ni++)
          hout[(size_t)row*Hc + wn*64 + ni*16 + lr] = hv[ni];
      }
      sc += __shfl_xor(sc,1); sc += __shfl_xor(sc,2);
      sc += __shfl_xor(sc,4); sc += __shfl_xor(sc,8);
      if (lr == 0) scds[rl][wn] = sc;
    }
  }
  __syncthreads();
  if (tid < 64){
    int row = m0 + tid;
    if (row < M) score[row] = tanhf((scds[tid][0] + scds[tid][1]) / nrm);
  }
}

// ---------------- per-graph top-k via bitonic sort (val desc, idx asc) -------
template<int N, int K, int NP2>
__global__ void k_topk(const float* __restrict__ score, int* __restrict__ newid,
                       int* __restrict__ perm){
  __shared__ float sv[NP2];
  __shared__ int   si[NP2];
  int g = blockIdx.x, t = threadIdx.x;
  sv[t] = (t < N) ? score[g*N + t] : -INFINITY;
  si[t] = t;
  __syncthreads();
  for (int k=2;k<=NP2;k<<=1){
    for (int j=k>>1;j>0;j>>=1){
      int p = t ^ j;
      if (p > t){
        float va = sv[t], vb = sv[p];
        int   ia = si[t], ib = si[p];
        bool good = (va > vb) || (va == vb && ia < ib);
        bool up   = ((t & k) == 0);
        if (good != up){ sv[t]=vb; si[t]=ib; sv[p]=va; si[p]=ia; }
      }
      __syncthreads();
    }
  }
  if (t < N) newid[g*N + t] = -1;
  __syncthreads();
  if (t < K){
    int old = si[t];
    newid[g*N + old] = g*K + t;
    perm[g*K + t]    = g*N + old;
  }
}

// ---------------- fused gather + split + readout: one block per graph --------
// 1024 thr = 8 row-groups x 128 cols. Streams hp rows once; accumulates
// per-graph max/mean inline (replaces separate k_readout re-read).
__launch_bounds__(1024)
__global__ void k_gatherR(const float* __restrict__ h, const float* __restrict__ score,
                          const int* __restrict__ perm, float* __restrict__ hp,
                          unsigned short* __restrict__ hpS, float* __restrict__ z,
                          int kk, int doSplit){
  __shared__ float smx[8][Hc];
  __shared__ float ssm[8][Hc];
  int g = blockIdx.x;
  int rg = threadIdx.x >> 7, j = threadIdx.x & 127;
  float mx = -INFINITY, sm = 0.f;
  for (int r=rg; r<kk; r+=8){
    int m = g*kk + r;
    int p = perm[m];
    float v = h[(size_t)p*Hc + j] * score[p];
    hp[(size_t)m*Hc + j] = v;
    float vn = __shfl_xor(v, 1);
    if (doSplit && !(j & 1)){
      unsigned short a0,a1,a2,b0,b1,b2;
      split3(v,  a0, a1, a2);
      split3(vn, b0, b1, b2);
      size_t fl = flIdx(m, j);
      *(unsigned*)&hpS[fl]        = (unsigned)a0 | ((unsigned)b0 << 16);
      *(unsigned*)&hpS[PL + fl]   = (unsigned)a1 | ((unsigned)b1 << 16);
      *(unsigned*)&hpS[2*PL + fl] = (unsigned)a2 | ((unsigned)b2 << 16);
    }
    mx = fmaxf(mx, v); sm += v;
  }
  smx[rg][j] = mx; ssm[rg][j] = sm;
  __syncthreads();
  if (rg == 0){
    #pragma unroll
    for (int u=1; u<8; u++){
      mx = fmaxf(mx, smx[u][j]); sm += ssm[u][j];
    }
    z[g*256 + j]       += mx;
    z[g*256 + 128 + j] += sm / (float)kk;
  }
}

// map2[o] = newid2[map1[o]] ; orig3[m] = perm1[perm2[m]]
__global__ void k_compose(const int* __restrict__ map1, const int* __restrict__ newid2,
                          int* __restrict__ map2, const int* __restrict__ perm1,
                          const int* __restrict__ perm2, int* __restrict__ orig3){
  int o = blockIdx.x*256 + threadIdx.x;
  if (o < N0){ int m = map1[o]; map2[o] = (m>=0) ? newid2[m] : -1; }
  if (o < N2){ orig3[o] = perm1[perm2[o]]; }
}

// ---------------- layers 2/3 aggregation: compact list, paired float4 loads --
__global__ void k_aggHs(const int* __restrict__ orig, const int* __restrict__ map,
                        const float* __restrict__ hp,
                        const int* __restrict__ csr, const int* __restrict__ rowptr,
                        const int* __restrict__ deg, unsigned short* __restrict__ aggS,
                        int M){
  int cpx = gridDim.x >> 3;
  int bid = (int)((blockIdx.x & 7)*cpx + (blockIdx.x >> 3));
  int m = bid*4 + (threadIdx.x>>6);
  int lane = threadIdx.x & 63;
  if (m >= M) return;
  int d = orig[m];
  int rs = rowptr[d], dg = deg[d];
  int half = lane >> 5, cl = lane & 31;
  f32x4 acc[4];
  #pragma unroll
  for (int u=0;u<4;u++) acc[u] = (f32x4){0.f,0.f,0.f,0.f};
  for (int base=0; base<dg; base+=64){
    int e = base + lane;
    int ns = -1;
    if (e < dg){ int s = csr[rs+e]; ns = map[s]; }
    int cnt = min(64, dg-base);
    for (int jj=0; jj<cnt; jj+=8){
      #pragma unroll
      for (int u=0; u<4; u++){
        int ei = jj + u*2 + half;
        int nsj = __shfl(ns, ei & 63);
        if (ei < cnt && nsj >= 0){
          acc[u] += *(const f32x4*)(hp + (size_t)nsj*Hc + cl*4);
        }
      }
    }
  }
  f32x4 s4 = (acc[0]+acc[1]) + (acc[2]+acc[3]);
  #pragma unroll
  for (int i=0;i<4;i++) s4[i] += __shfl_xor(s4[i], 32);
  float e0 = __shfl(s4[0], lane>>1);
  float e1 = __shfl(s4[1], lane>>1);
  float e2 = __shfl(s4[2], lane>>1);
  float e3 = __shfl(s4[3], lane>>1);
  float cx = (lane&1) ? e2 : e0;
  float cy = (lane&1) ? e3 : e1;
  unsigned short x0,x1,x2,y0,y1,y2;
  split3(cx, x0, x1, x2);
  split3(cy, y0, y1, y2);
  size_t fl = flIdx(m, 2*lane);
  *(unsigned*)&aggS[fl]        = (unsigned)x0 | ((unsigned)y0 << 16);
  *(unsigned*)&aggS[PL + fl]   = (unsigned)x1 | ((unsigned)y1 << 16);
  *(unsigned*)&aggS[2*PL + fl] = (unsigned)x2 | ((unsigned)y2 << 16);
}

// ---------------- conv2/conv3: 6-term split MFMA, fused score ----------------
__launch_bounds__(256)
__global__ void k_convH(const unsigned short* __restrict__ A0s,
                        const unsigned short* __restrict__ A1s,
                        const unsigned short* __restrict__ Wsp,
                        const float* __restrict__ bias, const float* __restrict__ pw,
                        const float* __restrict__ norm_p,
                        float* __restrict__ hout, float* __restrict__ score, int M){
  __shared__ float scds[64][2];
  int tid = threadIdx.x;
  int w = tid >> 6, l = tid & 63;
  int wm = w >> 1, wn = w & 1;
  int lr = l & 15, lk = l >> 4;
  int m0 = blockIdx.x * 64;

  f32x4 acc[2][4];
  #pragma unroll
  for (int mi=0;mi<2;mi++)
    #pragma unroll
    for (int ni=0;ni<4;ni++) acc[mi][ni] = (f32x4){0.f,0.f,0.f,0.f};

  #pragma unroll
  for (int kc=0; kc<4; kc++){
    #pragma unroll
    for (int p=0; p<2; p++){
      const unsigned short* As = p ? A1s : A0s;
      const unsigned short* Wp = Wsp + (size_t)p*3*16384;
      s16x8 af[3][2], bf[3][4];
      #pragma unroll
      for (int mi=0; mi<2; mi++){
        int tile = (m0 + wm*32 + mi*16) >> 4;
        size_t idx = (size_t)tile*2048 + (size_t)(kc*4+lk)*128 + (size_t)lr*8;
        af[0][mi] = *(const s16x8*)&As[idx];
        af[1][mi] = *(const s16x8*)&As[PL + idx];
        af[2][mi] = *(const s16x8*)&As[2*PL + idx];
      }
      #pragma unroll
      for (int ni=0; ni<4; ni++){
        int ct = wn*4 + ni;
        size_t idx = (size_t)ct*2048 + (size_t)(kc*4+lk)*128 + (size_t)lr*8;
        bf[0][ni] = *(const s16x8*)&Wp[idx];
        bf[1][ni] = *(const s16x8*)&Wp[16384 + idx];
        bf[2][ni] = *(const s16x8*)&Wp[32768 + idx];
      }
      #define TRM(sa,sb) \
        _Pragma("unroll") \
        for (int ni=0; ni<4; ni++){ \
          _Pragma("unroll") \
          for (int mi=0; mi<2; mi++){ \
            acc[mi][ni] = __builtin_amdgcn_mfma_f32_16x16x32_bf16(af[sa][mi], bf[sb][ni], acc[mi][ni], 0,0,0); \
          } \
        }
      TRM(0,0) TRM(0,1) TRM(1,0) TRM(1,1) TRM(0,2) TRM(2,0)
      #undef TRM
    }
  }

  float nrm = *norm_p;
  float pwv[4], biasv[4];
  #pragma unroll
  for (int ni=0;ni<4;ni++){
    int col = wn*64 + ni*16 + lr;
    pwv[ni] = pw[col]; biasv[ni] = bias[col];
  }
  #pragma unroll
  for (int mi=0; mi<2; mi++){
    #pragma unroll
    for (int reg=0; reg<4; reg++){
      int rl = wm*32 + mi*16 + lk*4 + reg;
      int row = m0 + rl;
      float hv[4]; float sc = 0.f;
      #pragma unroll
      for (int ni=0; ni<4; ni++){
        hv[ni] = fmaxf(acc[mi][ni][reg] + biasv[ni], 0.f);
        sc += hv[ni]*pwv[ni];
      }
      if (row < M){
        #pragma unroll
        for (int ni=0; ni<4; ni++)
          hout[(size_t)row*Hc + wn*64 + ni*16 + lr] = hv[ni];
      }
      sc += __shfl_xor(sc,1); sc += __shfl_xor(sc,2);
      sc += __shfl_xor(sc,4); sc += __shfl_xor(sc,8);
      if (lr == 0) scds[rl][wn] = sc;
    }
  }
  __syncthreads();
  if (tid < 64){
    int row = m0 + tid;
    if (row < M) score[row] = tanhf((scds[tid][0] + scds[tid][1]) / nrm);
  }
}

// ---------------- MLP head ---------------------------------------------------
__launch_bounds__(512)
__global__ void k_mlp(const float* __restrict__ z,
                      const float* __restrict__ Wl1T, const float* __restrict__ bl1,
                      const float* __restrict__ Wl2T, const float* __restrict__ bl2,
                      const float* __restrict__ Wl3, const float* __restrict__ bl3,
                      float* __restrict__ out){
  __shared__ float zs[256];
  __shared__ float u1[512];
  int g = blockIdx.x, t = threadIdx.x;
  if (t < 256) zs[t] = z[g*256 + t];
  __syncthreads();
  {
    float acc = bl1[t];
    #pragma unroll 8
    for (int f=0; f<256; f++) acc = fmaf(zs[f], Wl1T[f*512 + t], acc);
    u1[t] = fmaxf(acc, 0.f);
  }
  __syncthreads();
  if (t < 64){
    float acc = bl2[t];
    #pragma unroll 8
    for (int f=0; f<512; f++) acc = fmaf(u1[f], Wl2T[f*64 + t], acc);
    float v = fmaxf(acc, 0.f) * Wl3[t];
    for (int o=32;o>0;o>>=1) v += __shfl_xor(v, o);
    if (t == 0) out[g] = v + bl3[0];
  }
}

extern "C" void kernel_launch(void* const* d_in, const int* in_sizes, int n_in,
                              void* d_out, int out_size, void* d_ws, size_t ws_size,
                              hipStream_t stream){
  const float* x     = (const float*)d_in[0];
  const int*   esrc  = (const int*)d_in[1];
  const int*   edst  = (const int*)d_in[2];
  const float* Wrel1 = (const float*)d_in[5];
  const float* Wroot1= (const float*)d_in[6];
  const float* b1    = (const float*)d_in[7];
  const float* pw1   = (const float*)d_in[8];
  const float* Wrel2 = (const float*)d_in[9];
  const float* Wroot2= (const float*)d_in[10];
  const float* b2    = (const float*)d_in[11];
  const float* pw2   = (const float*)d_in[12];
  const float* Wrel3 = (const float*)d_in[13];
  const float* Wroot3= (const float*)d_in[14];
  const float* b3    = (const float*)d_in[15];
  const float* pw3   = (const float*)d_in[16];
  const float* Wl1   = (const float*)d_in[17];
  const float* bl1   = (const float*)d_in[18];
  const float* Wl2   = (const float*)d_in[19];
  const float* bl2   = (const float*)d_in[20];
  const float* Wl3   = (const float*)d_in[21];
  const float* bl3   = (const float*)d_in[22];
  float* out = (float*)d_out;

  char* ws = (char*)d_ws;
  size_t off = 0;
  auto alloc = [&](size_t elems)->void*{
    void* p = ws + off;
    off += ((elems*4 + 255)/256)*256;
    return p;
  };
  int*   deg    = (int*)alloc(N0);
  int*   rowptr = (int*)alloc(N0);
  int*   csr    = (int*)alloc(NE);
  int*   map1   = (int*)alloc(N0);
  int*   newid2 = (int*)alloc(N1);
  int*   map2   = (int*)alloc(N0);
  int*   perm1  = (int*)alloc(N1);
  int*   perm2  = (int*)alloc(N2);
  int*   perm3  = (int*)alloc(N3);
  int*   orig3  = (int*)alloc(N2);
  float* score1 = (float*)alloc(N0);
  float* score2 = (float*)alloc(N1);
  float* score3 = (float*)alloc(N2);
  float* agg1   = (float*)alloc((size_t)N0*FINc);
  float* Wl1T   = (float*)alloc(256*512);
  float* Wl2T   = (float*)alloc(512*64);
  unsigned short* Wsp = (unsigned short*)alloc(98304);   // 196608 bf16
  unsigned short* W1S = (unsigned short*)alloc(6144);    // 12288 bf16
  float* norms  = (float*)alloc(3);
  float* bigA   = (float*)alloc((size_t)N0*Hc);      // h1, then aggS (3 planes)
  float* hB     = (float*)alloc((size_t)N1*Hc);      // h2 -> h3
  float* hpA    = (float*)alloc((size_t)N1*Hc);      // hp f32 row-major
  unsigned short* hpS = (unsigned short*)alloc((size_t)3*N1*Hc/2);  // 3 planes, frag layout
  float* z      = (float*)alloc(BG*256);

  float* h1   = bigA;
  unsigned short* aggS = (unsigned short*)bigA;   // h1 dead by then
  unsigned short* a1S  = hpS;                     // dead before gather fills hpS
  float* h2   = hB;
  float* h3   = hB;

  hipMemsetAsync(z, 0, BG*256*sizeof(float), stream);

  // CSR build (one kernel) + weight prep
  k_csr    <<<BG, 512, 0, stream>>>(esrc, edst, deg, rowptr, csr);
  k_prep   <<<512, 256, 0, stream>>>(Wl1, Wl2, Wl1T, Wl2T);
  k_prepw  <<<256, 256, 0, stream>>>(Wrel2, Wroot2, Wrel3, Wroot3, Wsp);
  k_prepw1 <<<16, 256, 0, stream>>>(Wrel1, Wroot1, W1S);
  k_pwnorm <<<1, 384, 0, stream>>>(pw1, pw2, pw3, norms);

  // layer 1
  k_agg1   <<<N0/4, 256, 0, stream>>>(x, csr, rowptr, deg, agg1);
  k_splitA <<<N0*16/256, 256, 0, stream>>>(x, agg1, a1S);
  k_conv1m <<<N0/64, 256, 0, stream>>>(a1S, W1S, b1, pw1, norms+0, h1, score1, N0);
  k_topk<NPGc, K1c, 512><<<BG, 512, 0, stream>>>(score1, map1, perm1);
  k_gatherR<<<BG, 1024, 0, stream>>>(h1, score1, perm1, hpA, hpS, z, K1c, 1);

  // layer 2
  k_aggHs  <<<N1/4, 256, 0, stream>>>(perm1, map1, hpA, csr, rowptr, deg, aggS, N1);
  k_convH  <<<N1/64, 256, 0, stream>>>(aggS, hpS, Wsp, b2, pw2, norms+1, h2, score2, N1);
  k_topk<K1c, K2c, 256><<<BG, 256, 0, stream>>>(score2, newid2, perm2);
  k_compose<<<N0/256, 256, 0, stream>>>(map1, newid2, map2, perm1, perm2, orig3);
  k_gatherR<<<BG, 1024, 0, stream>>>(h2, score2, perm2, hpA, hpS, z, K2c, 1);

  // layer 3  (grid padded to x8 for bijective XCD swizzle)
  k_aggHs  <<<10256, 256, 0, stream>>>(orig3, map2, hpA, csr, rowptr, deg, aggS, N2);
  k_convH  <<<(N2+63)/64, 256, 0, stream>>>(aggS, hpS, Wsp + 98304, b3, pw3, norms+2, h3, score3, N2);
  k_topk<K2c, K3c, 256><<<BG, 256, 0, stream>>>(score3, newid2, perm3);
  k_gatherR<<<BG, 1024, 0, stream>>>(h3, score3, perm3, hpA, hpS, z, K3c, 0);

  // head
  k_mlp<<<BG, 512, 0, stream>>>(z, Wl1T, bl1, Wl2T, bl2, Wl3, bl3, out);
}